// Round 8
// baseline (540.603 us; speedup 1.0000x reference)
//
#include <hip/hip_runtime.h>
#include <cstdint>
#include <cstddef>

#define NN      50000
#define MPAD    50048   // NN padded to 128
#define EE      800000
#define NHEADS  8
#define HID_TOT 512
#define NCLASS  64
#define ALPHA_LRELU 0.2f
#define NB1     196     // cdiv(NN,256)

typedef unsigned short u16;
typedef __attribute__((ext_vector_type(8))) unsigned short ushort8;
typedef __attribute__((ext_vector_type(4))) unsigned short ushort4v;

__device__ __forceinline__ float bf2f(u16 v) {
    return __uint_as_float(((unsigned)v) << 16);
}
__device__ __forceinline__ u16 f2bf(float f) {   // round-to-nearest-even
    unsigned u = __float_as_uint(f);
    return (u16)((u + 0x7fffu + ((u >> 16) & 1u)) >> 16);
}

// -------------------- fused prep: cast_x + pack_w1t + pack_woutt + zero_cnt --------------------
#define PREP_R0 (MPAD * 64)          // cast_x groups (8 elems each)
#define PREP_R1 (512 * 512)          // pack_w1t elems
#define PREP_R2 (64 * 512)           // pack_woutt elems
#define PREP_R3 (NN / 4)             // cnt zero groups (int4 each)
#define PREP_TOT (PREP_R0 + PREP_R1 + PREP_R2 + PREP_R3)

__global__ __launch_bounds__(256) void prep_all(const float* __restrict__ x,
                                                const float* __restrict__ W,
                                                const float* __restrict__ W_out,
                                                u16* __restrict__ xb,
                                                u16* __restrict__ Wt1,
                                                u16* __restrict__ Wto,
                                                int* __restrict__ cnt) {
    int g = blockIdx.x * 256 + threadIdx.x;
    if (g < PREP_R0) {
        int r = g >> 6;
        int c = (g & 63) * 8;
        ushort8 o = (ushort8)0;
        if (r < NN) {
            const float4 v0 = *(const float4*)(x + (size_t)r * 512 + c);
            const float4 v1 = *(const float4*)(x + (size_t)r * 512 + c + 4);
            o[0] = f2bf(v0.x); o[1] = f2bf(v0.y); o[2] = f2bf(v0.z); o[3] = f2bf(v0.w);
            o[4] = f2bf(v1.x); o[5] = f2bf(v1.y); o[6] = f2bf(v1.z); o[7] = f2bf(v1.w);
        }
        *(ushort8*)(xb + (size_t)r * 512 + c) = o;
        return;
    }
    g -= PREP_R0;
    if (g < PREP_R1) {
        int c = g >> 9, f = g & 511;
        int h = c >> 6, j = c & 63;
        Wt1[g] = f2bf(W[(h << 15) + (f << 6) + j]);
        return;
    }
    g -= PREP_R1;
    if (g < PREP_R2) {
        int n = g >> 9, k = g & 511;
        Wto[g] = f2bf(W_out[k * 64 + n]);
        return;
    }
    g -= PREP_R2;
    if (g < PREP_R3) {
        *(int4*)(cnt + g * 4) = make_int4(0, 0, 0, 0);
    }
}

// -------------------- CSR build --------------------

__global__ void hist_rows(const int* __restrict__ row, int* __restrict__ cnt) {
    int e = blockIdx.x * 256 + threadIdx.x;
    if (e >= EE) return;
    atomicAdd(&cnt[row[e]], 1);
}

__global__ __launch_bounds__(256) void scan_blocksum(const int* __restrict__ cnt,
                                                     int* __restrict__ bsum) {
    int idx = blockIdx.x * 256 + threadIdx.x;
    int v = (idx < NN) ? cnt[idx] : 0;
    #pragma unroll
    for (int o = 32; o; o >>= 1) v += __shfl_xor(v, o);
    __shared__ int sw[4];
    int wave = threadIdx.x >> 6;
    if ((threadIdx.x & 63) == 0) sw[wave] = v;
    __syncthreads();
    if (threadIdx.x == 0) bsum[blockIdx.x] = sw[0] + sw[1] + sw[2] + sw[3];
}

__global__ __launch_bounds__(256) void scan_bsums(const int* __restrict__ bsum,
                                                  int* __restrict__ boff) {
    __shared__ int sh[256];
    int t = threadIdx.x;
    int v = (t < NB1) ? bsum[t] : 0;
    sh[t] = v;
    __syncthreads();
    for (int o = 1; o < 256; o <<= 1) {
        int cur = sh[t];
        int add = (t >= o) ? sh[t - o] : 0;
        __syncthreads();
        sh[t] = cur + add;
        __syncthreads();
    }
    if (t < NB1) boff[t] = sh[t] - v;   // exclusive
}

__global__ __launch_bounds__(256) void scan_write(const int* __restrict__ cnt,
                                                  const int* __restrict__ boff,
                                                  int* __restrict__ start,
                                                  int* __restrict__ wr) {
    __shared__ int sh[256];
    int t = threadIdx.x;
    int idx = blockIdx.x * 256 + t;
    int c = (idx < NN) ? cnt[idx] : 0;
    sh[t] = c;
    __syncthreads();
    for (int o = 1; o < 256; o <<= 1) {
        int cur = sh[t];
        int add = (t >= o) ? sh[t - o] : 0;
        __syncthreads();
        sh[t] = cur + add;
        __syncthreads();
    }
    if (idx < NN) {
        int excl = boff[blockIdx.x] + sh[t] - c;
        start[idx] = excl;
        wr[idx] = excl;
    }
    if (idx == 0) start[NN] = EE;
}

__global__ void scatter_edges(const int* __restrict__ row, const int* __restrict__ col,
                              int* __restrict__ wr, int* __restrict__ ecol) {
    int e = blockIdx.x * 256 + threadIdx.x;
    if (e >= EE) return;
    int i = row[e];
    int pos = atomicAdd(&wr[i], 1);
    ecol[pos] = col[e];
}

// -------------------- bf16 MFMA GEMM with fused attention-dot epilogues --------------------

__device__ __forceinline__ void load_lds_128(const u16* g, u16* l) {
    __builtin_amdgcn_global_load_lds((const __attribute__((address_space(1))) void*)g,
                                     (__attribute__((address_space(3))) void*)l,
                                     16, 0, 0);
}

typedef __attribute__((ext_vector_type(8))) short frag8;
typedef __attribute__((ext_vector_type(4))) float f32x4;

// Grid: blockIdx.x = M-panel (bm), blockIdx.y = N-block (bn) — XCD-friendly A locality.
// OUT_MODE: 0 = f32 node-major, 1 = bf16 node-major.
// FUSE: 0 none; 1 = per-head dots (requires BN=128, N=512); 2 = full-row dots (BN=64, N=64).
template <int BN, int OUT_MODE, int FUSE>
__global__ __launch_bounds__(256) void gemm_bf16(const u16* __restrict__ A,
                                                 const u16* __restrict__ Bt,
                                                 void* __restrict__ Cv,
                                                 int M, int N, int K,
                                                 const float* __restrict__ av,
                                                 float* __restrict__ fd,
                                                 float* __restrict__ fs) {
    constexpr int BM = 128, BK = 32;
    constexpr int WN = BN / 2;
    constexpr int NT = WN / 16;
    __shared__ u16 As[BM * BK];
    __shared__ u16 Bs[BN * BK];
    __shared__ float pd[2][2][64];
    __shared__ float ps[2][2][64];
    const int tid = threadIdx.x;
    const int wave = tid >> 6, lane = tid & 63;
    const int wm = wave & 1, wn = wave >> 1;
    const int bm = blockIdx.x * BM, bn = blockIdx.y * BN;
    const int q = lane >> 4, lr = lane & 15;

    f32x4 acc[4][NT] = {};

    for (int k0 = 0; k0 < K; k0 += BK) {
        #pragma unroll
        for (int c = wave; c < (BM * BK) / 512; c += 4) {
            int f = c * 512 + lane * 8;
            int row = f >> 5, ck = f & 31;
            load_lds_128(A + (size_t)(bm + row) * K + k0 + ck, As + c * 512);
        }
        #pragma unroll
        for (int c = wave; c < (BN * BK) / 512; c += 4) {
            int f = c * 512 + lane * 8;
            int row = f >> 5, ck = f & 31;
            load_lds_128(Bt + (size_t)(bn + row) * K + k0 + ck, Bs + c * 512);
        }
        __syncthreads();
        frag8 af[4], bfr[NT];
        #pragma unroll
        for (int am = 0; am < 4; am++)
            af[am] = *(const frag8*)(As + (wm * 64 + am * 16 + lr) * 32 + q * 8);
        #pragma unroll
        for (int bt = 0; bt < NT; bt++)
            bfr[bt] = *(const frag8*)(Bs + (wn * WN + bt * 16 + lr) * 32 + q * 8);
        #pragma unroll
        for (int am = 0; am < 4; am++)
            #pragma unroll
            for (int bt = 0; bt < NT; bt++)
                acc[am][bt] = __builtin_amdgcn_mfma_f32_16x16x32_bf16(af[am], bfr[bt], acc[am][bt], 0, 0, 0);
        __syncthreads();
    }

    float adv[NT], adv2[NT];
    int hd = 0;
    if (FUSE == 1) {
        hd = blockIdx.y * 2 + wn;
        const float* ah = av + hd * 128;
        #pragma unroll
        for (int bt = 0; bt < NT; bt++) {
            adv[bt]  = ah[bt * 16 + lr];
            adv2[bt] = ah[64 + bt * 16 + lr];
        }
    }
    if (FUSE == 2) {
        #pragma unroll
        for (int bt = 0; bt < NT; bt++) {
            adv[bt]  = av[wn * WN + bt * 16 + lr];
            adv2[bt] = av[64 + wn * WN + bt * 16 + lr];
        }
    }

    #pragma unroll
    for (int am = 0; am < 4; am++) {
        #pragma unroll
        for (int reg = 0; reg < 4; reg++) {
            int gr = bm + wm * 64 + am * 16 + q * 4 + reg;
            bool inb = gr < M;
            if (inb) {
                #pragma unroll
                for (int bt = 0; bt < NT; bt++) {
                    int gc = bn + wn * WN + bt * 16 + lr;
                    float v = acc[am][bt][reg];
                    if (OUT_MODE == 0) ((float*)Cv)[(size_t)gr * N + gc] = v;
                    else               ((u16*)Cv)[(size_t)gr * N + gc] = f2bf(v);
                }
            }
            if (FUSE != 0) {
                float sd = 0.f, ss = 0.f;
                #pragma unroll
                for (int bt = 0; bt < NT; bt++) {
                    float v = acc[am][bt][reg];
                    sd += v * adv[bt];
                    ss += v * adv2[bt];
                }
                #pragma unroll
                for (int o = 1; o < 16; o <<= 1) {
                    sd += __shfl_xor(sd, o);
                    ss += __shfl_xor(ss, o);
                }
                if (FUSE == 1) {
                    if (lr == 0 && inb) {
                        fd[gr * 8 + hd] = sd;
                        fs[gr * 8 + hd] = ss;
                    }
                } else {
                    if (lr == 0) {
                        int rr = am * 16 + q * 4 + reg;
                        pd[wm][wn][rr] = sd;
                        ps[wm][wn][rr] = ss;
                    }
                }
            }
        }
    }
    if (FUSE == 2) {
        __syncthreads();
        if (tid < 128) {
            int wmm = tid >> 6, rr = tid & 63;
            int gr = bm + wmm * 64 + rr;
            if (gr < M) {
                fd[gr] = pd[wmm][0][rr] + pd[wmm][1][rr];
                fs[gr] = ps[wmm][0][rr] + ps[wmm][1][rr];
            }
        }
    }
}

// -------------------- single-pass softmax-gather (layer 1, head-sliced per XCD) --------------------
// wave = (node, head): hd = blockIdx.x & 7 so all blocks touching head hd land on the
// same XCD (round-robin dispatch) -> per-XCD L2 working set = one head slice (6.4 MB)
// instead of the full 50 MB Whb1. Lane = g*8 + r: 8 edge-groups x 8 dim-lanes;
// per group-iter one edge: ushort8 (16 B) load at Whb[j][hd*64 + r*8] (8 lanes = 128 B line).
// Cross-group reduce via shfl_xor(8,16,32); lanes g==0 write 128 B of h1b.
__global__ __launch_bounds__(256) void agg1_fused(const int* __restrict__ start,
                                                  const int* __restrict__ ecol,
                                                  const float* __restrict__ fd,
                                                  const float* __restrict__ fs,
                                                  const u16* __restrict__ Whb,
                                                  u16* __restrict__ h1b) {
    const int hd = blockIdx.x & 7;
    const int i = (blockIdx.x >> 3) * 4 + (threadIdx.x >> 6);
    const int lane = threadIdx.x & 63;
    const int g = lane >> 3, r = lane & 7;
    const int st = start[i], en = start[i + 1];
    const float fdv = fd[i * 8 + hd];
    const u16* Wh = Whb + (size_t)hd * 64 + (size_t)r * 8;

    float acc[8] = {};
    float den = 0.f;
    for (int t = st + g; t < en; t += 8) {
        int j = ecol[t];
        float v = fdv + fs[j * 8 + hd];
        v = v > 0.f ? v : ALPHA_LRELU * v;
        float p = __expf(v);
        den += p;
        ushort8 wv = *(const ushort8*)(Wh + (size_t)j * HID_TOT);
        #pragma unroll
        for (int k = 0; k < 8; k++) acc[k] += p * bf2f(wv[k]);
    }
    #pragma unroll
    for (int o = 8; o <= 32; o <<= 1) {
        den += __shfl_xor(den, o);
        #pragma unroll
        for (int k = 0; k < 8; k++) acc[k] += __shfl_xor(acc[k], o);
    }
    if (g == 0) {
        float rden = 1.0f / fmaxf(den, 1e-16f);
        ushort8 o8;
        #pragma unroll
        for (int k = 0; k < 8; k++) {
            float v = acc[k] * rden;
            v = v > 0.f ? v : (__expf(v) - 1.0f);
            o8[k] = f2bf(v);
        }
        *(ushort8*)(h1b + (size_t)i * HID_TOT + hd * 64 + r * 8) = o8;
    }
}

// -------------------- single-pass softmax-gather (layer 2) --------------------
__global__ __launch_bounds__(256) void agg2_fused(const int* __restrict__ start,
                                                  const int* __restrict__ ecol,
                                                  const float* __restrict__ fd,
                                                  const float* __restrict__ fs,
                                                  const u16* __restrict__ Wh2b,
                                                  float* __restrict__ out) {
    const int i = blockIdx.x * 4 + (threadIdx.x >> 6);
    const int lane = threadIdx.x & 63;
    const int g = lane >> 4, r = lane & 15;
    const int st = start[i], en = start[i + 1];
    const float fdv = fd[i];

    float acc[4] = {};
    float den = 0.f;
    for (int t = st + g; t < en; t += 4) {
        int j = ecol[t];
        float v = fdv + fs[j];
        v = v > 0.f ? v : ALPHA_LRELU * v;
        float p = __expf(v);
        den += p;
        ushort4v wv = *(const ushort4v*)(Wh2b + (size_t)j * NCLASS + r * 4);
        #pragma unroll
        for (int k = 0; k < 4; k++) acc[k] += p * bf2f(wv[k]);
    }
    #pragma unroll
    for (int o = 16; o <= 32; o <<= 1) {
        den += __shfl_xor(den, o);
        #pragma unroll
        for (int k = 0; k < 4; k++) acc[k] += __shfl_xor(acc[k], o);
    }
    if (g == 0) {
        float rden = 1.0f / fmaxf(den, 1e-16f);
        float4 o4;
        o4.x = acc[0] * rden; o4.y = acc[1] * rden;
        o4.z = acc[2] * rden; o4.w = acc[3] * rden;
        *(float4*)(out + (size_t)i * NCLASS + r * 4) = o4;
    }
}

// -------------------- launch --------------------

static inline int cdiv_l(long a, long b) { return (int)((a + b - 1) / b); }

extern "C" void kernel_launch(void* const* d_in, const int* in_sizes, int n_in,
                              void* d_out, int out_size, void* d_ws, size_t ws_size,
                              hipStream_t stream) {
    const float* x     = (const float*)d_in[0];
    const int*   row   = (const int*)d_in[1];
    const int*   col   = (const int*)d_in[2];
    const float* W     = (const float*)d_in[3];
    const float* a     = (const float*)d_in[4];
    const float* W_out = (const float*)d_in[5];
    const float* a_out = (const float*)d_in[6];
    float* out = (float*)d_out;

    char* wsb = (char*)d_ws;
    size_t off = 0;
    auto alloc = [&](size_t bytes) { char* p = wsb + off; off += (bytes + 255) & ~(size_t)255; return p; };
    u16*   xb     = (u16*)  alloc((size_t)MPAD * 512 * 2);
    u16*   Wcat_t = (u16*)  alloc((size_t)512 * 512 * 2);
    u16*   Wot_t  = (u16*)  alloc((size_t)64 * 512 * 2);
    u16*   Whb1   = (u16*)  alloc((size_t)NN * 512 * 2);
    float* fd1    = (float*)alloc((size_t)NN * 8 * 4);
    float* fs1    = (float*)alloc((size_t)NN * 8 * 4);
    u16*   h1b    = (u16*)  alloc((size_t)MPAD * 512 * 2);
    u16*   Wh2b   = (u16*)  alloc((size_t)NN * 64 * 2);
    float* fd2    = (float*)alloc((size_t)NN * 4);
    float* fs2    = (float*)alloc((size_t)NN * 4);
    int*   cnt    = (int*)  alloc((size_t)NN * 4);
    int*   startp = (int*)  alloc(((size_t)NN + 1) * 4);
    int*   wr     = (int*)  alloc((size_t)NN * 4);
    int*   ecol   = (int*)  alloc((size_t)EE * 4);
    int*   bsum   = (int*)  alloc((size_t)NB1 * 4);
    int*   boff   = (int*)  alloc((size_t)NB1 * 4);

    // ---- prep (cast + packs + cnt zero) ----
    prep_all<<<cdiv_l(PREP_TOT, 256), 256, 0, stream>>>(x, W, W_out, xb, Wcat_t, Wot_t, cnt);

    // ---- CSR build ----
    hist_rows<<<cdiv_l(EE, 256), 256, 0, stream>>>(row, cnt);
    scan_blocksum<<<NB1, 256, 0, stream>>>(cnt, bsum);
    scan_bsums<<<1, 256, 0, stream>>>(bsum, boff);
    scan_write<<<NB1, 256, 0, stream>>>(cnt, boff, startp, wr);
    scatter_edges<<<cdiv_l(EE, 256), 256, 0, stream>>>(row, col, wr, ecol);

    // ---- layer 1 ----
    {
        dim3 grid(cdiv_l(MPAD, 128), 512 / 128);
        gemm_bf16<128, 1, 1><<<grid, 256, 0, stream>>>(xb, Wcat_t, Whb1, NN, 512, 512,
                                                       a, fd1, fs1);
    }
    agg1_fused<<<(NN / 4) * 8, 256, 0, stream>>>(startp, ecol, fd1, fs1, Whb1, h1b);

    // ---- layer 2 ----
    {
        dim3 grid(cdiv_l(MPAD, 128), 1);
        gemm_bf16<64, 1, 2><<<grid, 256, 0, stream>>>(h1b, Wot_t, Wh2b, NN, 64, 512,
                                                      a_out, fd2, fs2);
    }
    agg2_fused<<<NN / 4, 256, 0, stream>>>(startp, ecol, fd2, fs2, Wh2b, out);
}

// Round 9
// 487.762 us; speedup vs baseline: 1.1083x; 1.1083x over previous
//
#include <hip/hip_runtime.h>
#include <cstdint>
#include <cstddef>

#define NN      50000
#define MPAD    50048   // NN padded to 128
#define EE      800000
#define NHEADS  8
#define HID_TOT 512
#define NCLASS  64
#define ALPHA_LRELU 0.2f
#define NB1     196     // cdiv(NN,256)
#define NSCAT   3125    // cdiv(EE,256) scatter blocks
#define GM1_M   391     // MPAD/128 panels in gemm1

typedef unsigned short u16;
typedef __attribute__((ext_vector_type(8))) unsigned short ushort8;
typedef __attribute__((ext_vector_type(4))) unsigned short ushort4v;

__device__ __forceinline__ float bf2f(u16 v) {
    return __uint_as_float(((unsigned)v) << 16);
}
__device__ __forceinline__ u16 f2bf(float f) {   // round-to-nearest-even
    unsigned u = __float_as_uint(f);
    return (u16)((u + 0x7fffu + ((u >> 16) & 1u)) >> 16);
}

// -------------------- fused prep: cast_x + pack_w1t + pack_woutt + hist --------------------
// hist region merged here (independent of cast/pack inputs): cnt is zeroed by a
// preceding hipMemsetAsync, so hist blocks can run concurrently with prep blocks.
#define PREP_R0 (MPAD * 64)          // cast_x groups (8 elems each)
#define PREP_R1 (512 * 512)          // pack_w1t elems
#define PREP_R2 (64 * 512)           // pack_woutt elems
#define PREP_TOT (PREP_R0 + PREP_R1 + PREP_R2 + EE)

__global__ __launch_bounds__(256) void prep_all(const float* __restrict__ x,
                                                const float* __restrict__ W,
                                                const float* __restrict__ W_out,
                                                u16* __restrict__ xb,
                                                u16* __restrict__ Wt1,
                                                u16* __restrict__ Wto,
                                                const int* __restrict__ row,
                                                int* __restrict__ cnt) {
    int g = blockIdx.x * 256 + threadIdx.x;
    if (g < PREP_R0) {
        int r = g >> 6;
        int c = (g & 63) * 8;
        ushort8 o = (ushort8)0;
        if (r < NN) {
            const float4 v0 = *(const float4*)(x + (size_t)r * 512 + c);
            const float4 v1 = *(const float4*)(x + (size_t)r * 512 + c + 4);
            o[0] = f2bf(v0.x); o[1] = f2bf(v0.y); o[2] = f2bf(v0.z); o[3] = f2bf(v0.w);
            o[4] = f2bf(v1.x); o[5] = f2bf(v1.y); o[6] = f2bf(v1.z); o[7] = f2bf(v1.w);
        }
        *(ushort8*)(xb + (size_t)r * 512 + c) = o;
        return;
    }
    g -= PREP_R0;
    if (g < PREP_R1) {
        int c = g >> 9, f = g & 511;
        int h = c >> 6, j = c & 63;
        Wt1[g] = f2bf(W[(h << 15) + (f << 6) + j]);
        return;
    }
    g -= PREP_R1;
    if (g < PREP_R2) {
        int n = g >> 9, k = g & 511;
        Wto[g] = f2bf(W_out[k * 64 + n]);
        return;
    }
    g -= PREP_R2;
    if (g < EE) {
        atomicAdd(&cnt[row[g]], 1);
    }
}

// -------------------- CSR build --------------------

__global__ __launch_bounds__(256) void scan_blocksum(const int* __restrict__ cnt,
                                                     int* __restrict__ bsum) {
    int idx = blockIdx.x * 256 + threadIdx.x;
    int v = (idx < NN) ? cnt[idx] : 0;
    #pragma unroll
    for (int o = 32; o; o >>= 1) v += __shfl_xor(v, o);
    __shared__ int sw[4];
    int wave = threadIdx.x >> 6;
    if ((threadIdx.x & 63) == 0) sw[wave] = v;
    __syncthreads();
    if (threadIdx.x == 0) bsum[blockIdx.x] = sw[0] + sw[1] + sw[2] + sw[3];
}

// scan_write with the inter-block offset computed inline (scan_bsums eliminated):
// each block sums bsum[0..blockIdx.x) itself (<=196 adds across the block).
__global__ __launch_bounds__(256) void scan_write(const int* __restrict__ cnt,
                                                  const int* __restrict__ bsum,
                                                  int* __restrict__ start,
                                                  int* __restrict__ wr) {
    __shared__ int sh[256];
    __shared__ int swb[4];
    int t = threadIdx.x;
    // exclusive offset of this block = sum of bsum[0..blockIdx.x)
    int vb = (t < NB1 && t < blockIdx.x) ? bsum[t] : 0;
    #pragma unroll
    for (int o = 32; o; o >>= 1) vb += __shfl_xor(vb, o);
    if ((t & 63) == 0) swb[t >> 6] = vb;
    __syncthreads();
    const int blockoff = swb[0] + swb[1] + swb[2] + swb[3];

    int idx = blockIdx.x * 256 + t;
    int c = (idx < NN) ? cnt[idx] : 0;
    __syncthreads();          // swb reads done before sh reuse barrier discipline
    sh[t] = c;
    __syncthreads();
    for (int o = 1; o < 256; o <<= 1) {
        int cur = sh[t];
        int add = (t >= o) ? sh[t - o] : 0;
        __syncthreads();
        sh[t] = cur + add;
        __syncthreads();
    }
    if (idx < NN) {
        int excl = blockoff + sh[t] - c;
        start[idx] = excl;
        wr[idx] = excl;
    }
    if (idx == 0) start[NN] = EE;
}

// -------------------- merged scatter_edges + gemm1 (independent: true overlap) --------------------
// blocks [0, NSCAT): edge scatter (atomics-bound).
// blocks [NSCAT, NSCAT + GM1_M*4): layer-1 GEMM, bid%GM1_M = M-panel (XCD-friendly),
// bid/GM1_M = N-block; FUSE-1 per-head dot epilogue (hd = nb*2 + wn).

__device__ __forceinline__ void load_lds_128(const u16* g, u16* l) {
    __builtin_amdgcn_global_load_lds((const __attribute__((address_space(1))) void*)g,
                                     (__attribute__((address_space(3))) void*)l,
                                     16, 0, 0);
}

typedef __attribute__((ext_vector_type(8))) short frag8;
typedef __attribute__((ext_vector_type(4))) float f32x4;

__global__ __launch_bounds__(256) void scat_gemm1(const int* __restrict__ row,
                                                  const int* __restrict__ col,
                                                  int* __restrict__ wr,
                                                  int* __restrict__ ecol,
                                                  const u16* __restrict__ A,
                                                  const u16* __restrict__ Bt,
                                                  u16* __restrict__ C,
                                                  const float* __restrict__ av,
                                                  float* __restrict__ fd,
                                                  float* __restrict__ fs) {
    constexpr int BM = 128, BN = 128, BK = 32, WN = 64, NT = 4;
    constexpr int M = NN, N = 512, K = 512;
    __shared__ u16 As[BM * BK];
    __shared__ u16 Bs[BN * BK];
    const int tid = threadIdx.x;

    if (blockIdx.x < NSCAT) {
        int e = blockIdx.x * 256 + tid;
        if (e < EE) {
            int i = row[e];
            int pos = atomicAdd(&wr[i], 1);
            ecol[pos] = col[e];
        }
        return;
    }
    const int bid = blockIdx.x - NSCAT;
    const int wave = tid >> 6, lane = tid & 63;
    const int wm = wave & 1, wn = wave >> 1;
    const int bm = (bid % GM1_M) * BM;
    const int bnb = bid / GM1_M;
    const int bn = bnb * BN;
    const int q = lane >> 4, lr = lane & 15;

    f32x4 acc[4][NT] = {};

    for (int k0 = 0; k0 < K; k0 += BK) {
        #pragma unroll
        for (int c = wave; c < (BM * BK) / 512; c += 4) {
            int f = c * 512 + lane * 8;
            int r_ = f >> 5, ck = f & 31;
            load_lds_128(A + (size_t)(bm + r_) * K + k0 + ck, As + c * 512);
        }
        #pragma unroll
        for (int c = wave; c < (BN * BK) / 512; c += 4) {
            int f = c * 512 + lane * 8;
            int r_ = f >> 5, ck = f & 31;
            load_lds_128(Bt + (size_t)(bn + r_) * K + k0 + ck, Bs + c * 512);
        }
        __syncthreads();
        frag8 af[4], bfr[NT];
        #pragma unroll
        for (int am = 0; am < 4; am++)
            af[am] = *(const frag8*)(As + (wm * 64 + am * 16 + lr) * 32 + q * 8);
        #pragma unroll
        for (int bt = 0; bt < NT; bt++)
            bfr[bt] = *(const frag8*)(Bs + (wn * WN + bt * 16 + lr) * 32 + q * 8);
        #pragma unroll
        for (int am = 0; am < 4; am++)
            #pragma unroll
            for (int bt = 0; bt < NT; bt++)
                acc[am][bt] = __builtin_amdgcn_mfma_f32_16x16x32_bf16(af[am], bfr[bt], acc[am][bt], 0, 0, 0);
        __syncthreads();
    }

    const int hd = bnb * 2 + wn;
    const float* ah = av + hd * 128;
    float adv[NT], adv2[NT];
    #pragma unroll
    for (int bt = 0; bt < NT; bt++) {
        adv[bt]  = ah[bt * 16 + lr];
        adv2[bt] = ah[64 + bt * 16 + lr];
    }

    #pragma unroll
    for (int am = 0; am < 4; am++) {
        #pragma unroll
        for (int reg = 0; reg < 4; reg++) {
            int gr = bm + wm * 64 + am * 16 + q * 4 + reg;
            bool inb = gr < M;
            if (inb) {
                #pragma unroll
                for (int bt = 0; bt < NT; bt++) {
                    int gc = bn + wn * WN + bt * 16 + lr;
                    C[(size_t)gr * N + gc] = f2bf(acc[am][bt][reg]);
                }
            }
            float sd = 0.f, ss = 0.f;
            #pragma unroll
            for (int bt = 0; bt < NT; bt++) {
                float v = acc[am][bt][reg];
                sd += v * adv[bt];
                ss += v * adv2[bt];
            }
            #pragma unroll
            for (int o = 1; o < 16; o <<= 1) {
                sd += __shfl_xor(sd, o);
                ss += __shfl_xor(ss, o);
            }
            if (lr == 0 && inb) {
                fd[gr * 8 + hd] = sd;
                fs[gr * 8 + hd] = ss;
            }
        }
    }
}

// -------------------- layer-2 GEMM (template, FUSE=2) --------------------
template <int BN, int OUT_MODE, int FUSE>
__global__ __launch_bounds__(256) void gemm_bf16(const u16* __restrict__ A,
                                                 const u16* __restrict__ Bt,
                                                 void* __restrict__ Cv,
                                                 int M, int N, int K,
                                                 const float* __restrict__ av,
                                                 float* __restrict__ fd,
                                                 float* __restrict__ fs) {
    constexpr int BM = 128, BK = 32;
    constexpr int WN = BN / 2;
    constexpr int NT = WN / 16;
    __shared__ u16 As[BM * BK];
    __shared__ u16 Bs[BN * BK];
    __shared__ float pd[2][2][64];
    __shared__ float ps[2][2][64];
    const int tid = threadIdx.x;
    const int wave = tid >> 6, lane = tid & 63;
    const int wm = wave & 1, wn = wave >> 1;
    const int bm = blockIdx.x * BM, bn = blockIdx.y * BN;
    const int q = lane >> 4, lr = lane & 15;

    f32x4 acc[4][NT] = {};

    for (int k0 = 0; k0 < K; k0 += BK) {
        #pragma unroll
        for (int c = wave; c < (BM * BK) / 512; c += 4) {
            int f = c * 512 + lane * 8;
            int row = f >> 5, ck = f & 31;
            load_lds_128(A + (size_t)(bm + row) * K + k0 + ck, As + c * 512);
        }
        #pragma unroll
        for (int c = wave; c < (BN * BK) / 512; c += 4) {
            int f = c * 512 + lane * 8;
            int row = f >> 5, ck = f & 31;
            load_lds_128(Bt + (size_t)(bn + row) * K + k0 + ck, Bs + c * 512);
        }
        __syncthreads();
        frag8 af[4], bfr[NT];
        #pragma unroll
        for (int am = 0; am < 4; am++)
            af[am] = *(const frag8*)(As + (wm * 64 + am * 16 + lr) * 32 + q * 8);
        #pragma unroll
        for (int bt = 0; bt < NT; bt++)
            bfr[bt] = *(const frag8*)(Bs + (wn * WN + bt * 16 + lr) * 32 + q * 8);
        #pragma unroll
        for (int am = 0; am < 4; am++)
            #pragma unroll
            for (int bt = 0; bt < NT; bt++)
                acc[am][bt] = __builtin_amdgcn_mfma_f32_16x16x32_bf16(af[am], bfr[bt], acc[am][bt], 0, 0, 0);
        __syncthreads();
    }

    float adv[NT], adv2[NT];
    int hd = 0;
    if (FUSE == 1) {
        hd = blockIdx.y * 2 + wn;
        const float* ah = av + hd * 128;
        #pragma unroll
        for (int bt = 0; bt < NT; bt++) {
            adv[bt]  = ah[bt * 16 + lr];
            adv2[bt] = ah[64 + bt * 16 + lr];
        }
    }
    if (FUSE == 2) {
        #pragma unroll
        for (int bt = 0; bt < NT; bt++) {
            adv[bt]  = av[wn * WN + bt * 16 + lr];
            adv2[bt] = av[64 + wn * WN + bt * 16 + lr];
        }
    }

    #pragma unroll
    for (int am = 0; am < 4; am++) {
        #pragma unroll
        for (int reg = 0; reg < 4; reg++) {
            int gr = bm + wm * 64 + am * 16 + q * 4 + reg;
            bool inb = gr < M;
            if (inb) {
                #pragma unroll
                for (int bt = 0; bt < NT; bt++) {
                    int gc = bn + wn * WN + bt * 16 + lr;
                    float v = acc[am][bt][reg];
                    if (OUT_MODE == 0) ((float*)Cv)[(size_t)gr * N + gc] = v;
                    else               ((u16*)Cv)[(size_t)gr * N + gc] = f2bf(v);
                }
            }
            if (FUSE != 0) {
                float sd = 0.f, ss = 0.f;
                #pragma unroll
                for (int bt = 0; bt < NT; bt++) {
                    float v = acc[am][bt][reg];
                    sd += v * adv[bt];
                    ss += v * adv2[bt];
                }
                #pragma unroll
                for (int o = 1; o < 16; o <<= 1) {
                    sd += __shfl_xor(sd, o);
                    ss += __shfl_xor(ss, o);
                }
                if (FUSE == 1) {
                    if (lr == 0 && inb) {
                        fd[gr * 8 + hd] = sd;
                        fs[gr * 8 + hd] = ss;
                    }
                } else {
                    if (lr == 0) {
                        int rr = am * 16 + q * 4 + reg;
                        pd[wm][wn][rr] = sd;
                        ps[wm][wn][rr] = ss;
                    }
                }
            }
        }
    }
    if (FUSE == 2) {
        __syncthreads();
        if (tid < 128) {
            int wmm = tid >> 6, rr = tid & 63;
            int gr = bm + wmm * 64 + rr;
            if (gr < M) {
                fd[gr] = pd[wmm][0][rr] + pd[wmm][1][rr];
                fs[gr] = ps[wmm][0][rr] + ps[wmm][1][rr];
            }
        }
    }
}

// -------------------- single-pass softmax-gather (layer 1) --------------------
// Round-7 form (best measured): wave = node; lane covers dims lane*8..+8
// (head hh = lane>>3); serial edges, unroll x2.
__global__ __launch_bounds__(256) void agg1_fused(const int* __restrict__ start,
                                                  const int* __restrict__ ecol,
                                                  const float* __restrict__ fd,
                                                  const float* __restrict__ fs,
                                                  const u16* __restrict__ Whb,
                                                  u16* __restrict__ h1b) {
    const int i = blockIdx.x * 4 + (threadIdx.x >> 6);
    const int lane = threadIdx.x & 63;
    const int hh = lane >> 3;
    const int st = start[i], en = start[i + 1];
    const float fdv = fd[i * 8 + hh];

    float acc[8] = {};
    float den = 0.f;
    int t = st;
    for (; t + 2 <= en; t += 2) {
        int j0 = ecol[t], j1 = ecol[t + 1];
        float v0 = fdv + fs[j0 * 8 + hh]; v0 = v0 > 0.f ? v0 : ALPHA_LRELU * v0;
        float v1 = fdv + fs[j1 * 8 + hh]; v1 = v1 > 0.f ? v1 : ALPHA_LRELU * v1;
        float p0 = __expf(v0);
        float p1 = __expf(v1);
        ushort8 w0 = *(const ushort8*)(Whb + (size_t)j0 * HID_TOT + lane * 8);
        ushort8 w1 = *(const ushort8*)(Whb + (size_t)j1 * HID_TOT + lane * 8);
        den += p0 + p1;
        #pragma unroll
        for (int k = 0; k < 8; k++) acc[k] += p0 * bf2f(w0[k]);
        #pragma unroll
        for (int k = 0; k < 8; k++) acc[k] += p1 * bf2f(w1[k]);
    }
    if (t < en) {
        int j = ecol[t];
        float v = fdv + fs[j * 8 + hh]; v = v > 0.f ? v : ALPHA_LRELU * v;
        float p = __expf(v);
        den += p;
        ushort8 wv = *(const ushort8*)(Whb + (size_t)j * HID_TOT + lane * 8);
        #pragma unroll
        for (int k = 0; k < 8; k++) acc[k] += p * bf2f(wv[k]);
    }
    float rden = 1.0f / fmaxf(den, 1e-16f);
    ushort8 o8;
    #pragma unroll
    for (int k = 0; k < 8; k++) {
        float v = acc[k] * rden;
        v = v > 0.f ? v : (__expf(v) - 1.0f);
        o8[k] = f2bf(v);
    }
    *(ushort8*)(h1b + (size_t)i * HID_TOT + lane * 8) = o8;
}

// -------------------- single-pass softmax-gather (layer 2) --------------------
__global__ __launch_bounds__(256) void agg2_fused(const int* __restrict__ start,
                                                  const int* __restrict__ ecol,
                                                  const float* __restrict__ fd,
                                                  const float* __restrict__ fs,
                                                  const u16* __restrict__ Wh2b,
                                                  float* __restrict__ out) {
    const int i = blockIdx.x * 4 + (threadIdx.x >> 6);
    const int lane = threadIdx.x & 63;
    const int g = lane >> 4, r = lane & 15;
    const int st = start[i], en = start[i + 1];
    const float fdv = fd[i];

    float acc[4] = {};
    float den = 0.f;
    for (int t = st + g; t < en; t += 4) {
        int j = ecol[t];
        float v = fdv + fs[j];
        v = v > 0.f ? v : ALPHA_LRELU * v;
        float p = __expf(v);
        den += p;
        ushort4v wv = *(const ushort4v*)(Wh2b + (size_t)j * NCLASS + r * 4);
        #pragma unroll
        for (int k = 0; k < 4; k++) acc[k] += p * bf2f(wv[k]);
    }
    #pragma unroll
    for (int o = 16; o <= 32; o <<= 1) {
        den += __shfl_xor(den, o);
        #pragma unroll
        for (int k = 0; k < 4; k++) acc[k] += __shfl_xor(acc[k], o);
    }
    if (g == 0) {
        float rden = 1.0f / fmaxf(den, 1e-16f);
        float4 o4;
        o4.x = acc[0] * rden; o4.y = acc[1] * rden;
        o4.z = acc[2] * rden; o4.w = acc[3] * rden;
        *(float4*)(out + (size_t)i * NCLASS + r * 4) = o4;
    }
}

// -------------------- launch --------------------

static inline int cdiv_l(long a, long b) { return (int)((a + b - 1) / b); }

extern "C" void kernel_launch(void* const* d_in, const int* in_sizes, int n_in,
                              void* d_out, int out_size, void* d_ws, size_t ws_size,
                              hipStream_t stream) {
    const float* x     = (const float*)d_in[0];
    const int*   row   = (const int*)d_in[1];
    const int*   col   = (const int*)d_in[2];
    const float* W     = (const float*)d_in[3];
    const float* a     = (const float*)d_in[4];
    const float* W_out = (const float*)d_in[5];
    const float* a_out = (const float*)d_in[6];
    float* out = (float*)d_out;

    char* wsb = (char*)d_ws;
    size_t off = 0;
    auto alloc = [&](size_t bytes) { char* p = wsb + off; off += (bytes + 255) & ~(size_t)255; return p; };
    u16*   xb     = (u16*)  alloc((size_t)MPAD * 512 * 2);
    u16*   Wcat_t = (u16*)  alloc((size_t)512 * 512 * 2);
    u16*   Wot_t  = (u16*)  alloc((size_t)64 * 512 * 2);
    u16*   Whb1   = (u16*)  alloc((size_t)NN * 512 * 2);
    float* fd1    = (float*)alloc((size_t)NN * 8 * 4);
    float* fs1    = (float*)alloc((size_t)NN * 8 * 4);
    u16*   h1b    = (u16*)  alloc((size_t)MPAD * 512 * 2);
    u16*   Wh2b   = (u16*)  alloc((size_t)NN * 64 * 2);
    float* fd2    = (float*)alloc((size_t)NN * 4);
    float* fs2    = (float*)alloc((size_t)NN * 4);
    int*   cnt    = (int*)  alloc((size_t)NN * 4);
    int*   startp = (int*)  alloc(((size_t)NN + 1) * 4);
    int*   wr     = (int*)  alloc((size_t)NN * 4);
    int*   ecol   = (int*)  alloc((size_t)EE * 4);
    int*   bsum   = (int*)  alloc((size_t)NB1 * 4);
    int*   boff   = (int*)  alloc((size_t)NB1 * 4);
    (void)boff;

    // ---- zero cnt (memset node), then prep ∥ hist in one kernel ----
    hipMemsetAsync(cnt, 0, (size_t)NN * 4, stream);
    prep_all<<<cdiv_l(PREP_TOT, 256), 256, 0, stream>>>(x, W, W_out, xb, Wcat_t, Wot_t,
                                                        row, cnt);

    // ---- CSR scan (2 kernels; boff inlined into scan_write) ----
    scan_blocksum<<<NB1, 256, 0, stream>>>(cnt, bsum);
    scan_write<<<NB1, 256, 0, stream>>>(cnt, bsum, startp, wr);

    // ---- scatter ∥ layer-1 GEMM (independent; merged for overlap) ----
    scat_gemm1<<<NSCAT + GM1_M * 4, 256, 0, stream>>>(row, col, wr, ecol,
                                                      xb, Wcat_t, Whb1, a, fd1, fs1);

    agg1_fused<<<NN / 4, 256, 0, stream>>>(startp, ecol, fd1, fs1, Whb1, h1b);

    // ---- layer 2 ----
    {
        dim3 grid(cdiv_l(MPAD, 128), 1);
        gemm_bf16<64, 1, 2><<<grid, 256, 0, stream>>>(h1b, Wot_t, Wh2b, NN, 64, 512,
                                                      a_out, fd2, fs2);
    }
    agg2_fused<<<NN / 4, 256, 0, stream>>>(startp, ecol, fd2, fs2, Wh2b, out);
}

// Round 10
// 472.191 us; speedup vs baseline: 1.1449x; 1.0330x over previous
//
#include <hip/hip_runtime.h>
#include <cstdint>
#include <cstddef>

#define NN      50000
#define MPAD    50048   // NN padded to 128
#define EE      800000
#define NHEADS  8
#define HID_TOT 512
#define NCLASS  64
#define ALPHA_LRELU 0.2f
#define NB1     196     // cdiv(NN,256)
#define GM1_M   391     // MPAD/128 panels in gemm1
#define GM1_B   (GM1_M * 4)   // 1564 blocks; x2 edges/thread covers EE=800000

typedef unsigned short u16;
typedef __attribute__((ext_vector_type(8))) unsigned short ushort8;
typedef __attribute__((ext_vector_type(4))) unsigned short ushort4v;

__device__ __forceinline__ float bf2f(u16 v) {
    return __uint_as_float(((unsigned)v) << 16);
}
__device__ __forceinline__ u16 f2bf(float f) {   // round-to-nearest-even
    unsigned u = __float_as_uint(f);
    return (u16)((u + 0x7fffu + ((u >> 16) & 1u)) >> 16);
}

// -------------------- fused prep: cast_x + pack_w1t + pack_woutt + hist --------------------
#define PREP_R0 (MPAD * 64)          // cast_x groups (8 elems each)
#define PREP_R1 (512 * 512)          // pack_w1t elems
#define PREP_R2 (64 * 512)           // pack_woutt elems
#define PREP_TOT (PREP_R0 + PREP_R1 + PREP_R2 + EE)

__global__ __launch_bounds__(256) void prep_all(const float* __restrict__ x,
                                                const float* __restrict__ W,
                                                const float* __restrict__ W_out,
                                                u16* __restrict__ xb,
                                                u16* __restrict__ Wt1,
                                                u16* __restrict__ Wto,
                                                const int* __restrict__ row,
                                                int* __restrict__ cnt) {
    int g = blockIdx.x * 256 + threadIdx.x;
    if (g < PREP_R0) {
        int r = g >> 6;
        int c = (g & 63) * 8;
        ushort8 o = (ushort8)0;
        if (r < NN) {
            const float4 v0 = *(const float4*)(x + (size_t)r * 512 + c);
            const float4 v1 = *(const float4*)(x + (size_t)r * 512 + c + 4);
            o[0] = f2bf(v0.x); o[1] = f2bf(v0.y); o[2] = f2bf(v0.z); o[3] = f2bf(v0.w);
            o[4] = f2bf(v1.x); o[5] = f2bf(v1.y); o[6] = f2bf(v1.z); o[7] = f2bf(v1.w);
        }
        *(ushort8*)(xb + (size_t)r * 512 + c) = o;
        return;
    }
    g -= PREP_R0;
    if (g < PREP_R1) {
        int c = g >> 9, f = g & 511;
        int h = c >> 6, j = c & 63;
        Wt1[g] = f2bf(W[(h << 15) + (f << 6) + j]);
        return;
    }
    g -= PREP_R1;
    if (g < PREP_R2) {
        int n = g >> 9, k = g & 511;
        Wto[g] = f2bf(W_out[k * 64 + n]);
        return;
    }
    g -= PREP_R2;
    if (g < EE) {
        atomicAdd(&cnt[row[g]], 1);
    }
}

// -------------------- CSR build --------------------

__global__ __launch_bounds__(256) void scan_blocksum(const int* __restrict__ cnt,
                                                     int* __restrict__ bsum) {
    int idx = blockIdx.x * 256 + threadIdx.x;
    int v = (idx < NN) ? cnt[idx] : 0;
    #pragma unroll
    for (int o = 32; o; o >>= 1) v += __shfl_xor(v, o);
    __shared__ int sw[4];
    int wave = threadIdx.x >> 6;
    if ((threadIdx.x & 63) == 0) sw[wave] = v;
    __syncthreads();
    if (threadIdx.x == 0) bsum[blockIdx.x] = sw[0] + sw[1] + sw[2] + sw[3];
}

// scan_write with the inter-block offset computed inline (scan_bsums eliminated).
__global__ __launch_bounds__(256) void scan_write(const int* __restrict__ cnt,
                                                  const int* __restrict__ bsum,
                                                  int* __restrict__ start,
                                                  int* __restrict__ wr) {
    __shared__ int sh[256];
    __shared__ int swb[4];
    int t = threadIdx.x;
    int vb = (t < NB1 && t < blockIdx.x) ? bsum[t] : 0;
    #pragma unroll
    for (int o = 32; o; o >>= 1) vb += __shfl_xor(vb, o);
    if ((t & 63) == 0) swb[t >> 6] = vb;
    __syncthreads();
    const int blockoff = swb[0] + swb[1] + swb[2] + swb[3];

    int idx = blockIdx.x * 256 + t;
    int c = (idx < NN) ? cnt[idx] : 0;
    __syncthreads();
    sh[t] = c;
    __syncthreads();
    for (int o = 1; o < 256; o <<= 1) {
        int cur = sh[t];
        int add = (t >= o) ? sh[t - o] : 0;
        __syncthreads();
        sh[t] = cur + add;
        __syncthreads();
    }
    if (idx < NN) {
        int excl = blockoff + sh[t] - c;
        start[idx] = excl;
        wr[idx] = excl;
    }
    if (idx == 0) start[NN] = EE;
}

// -------------------- gemm1 with scatter folded into every block --------------------
// Each thread owns 2 edges: atomics issued in the prologue (returns unused), K-loop
// hides the round-trip, ecol scatter-writes land after the K-loop. Scatter cost ~ 0.

__device__ __forceinline__ void load_lds_128(const u16* g, u16* l) {
    __builtin_amdgcn_global_load_lds((const __attribute__((address_space(1))) void*)g,
                                     (__attribute__((address_space(3))) void*)l,
                                     16, 0, 0);
}

typedef __attribute__((ext_vector_type(8))) short frag8;
typedef __attribute__((ext_vector_type(4))) float f32x4;

__global__ __launch_bounds__(256) void scat_gemm1(const int* __restrict__ row,
                                                  const int* __restrict__ col,
                                                  int* __restrict__ wr,
                                                  int* __restrict__ ecol,
                                                  const u16* __restrict__ A,
                                                  const u16* __restrict__ Bt,
                                                  u16* __restrict__ C,
                                                  const float* __restrict__ av,
                                                  float* __restrict__ fd,
                                                  float* __restrict__ fs) {
    constexpr int BM = 128, BN = 128, BK = 32, WN = 64, NT = 4;
    constexpr int M = NN, N = 512, K = 512;
    __shared__ u16 As[BM * BK];
    __shared__ u16 Bs[BN * BK];
    const int tid = threadIdx.x;
    const int bid = blockIdx.x;

    // ---- scatter prologue: issue atomics, defer the dependent writes ----
    const int e0 = (bid * 256 + tid) * 2;
    int sc0 = 0, sc1 = 0, sp0 = 0, sp1 = 0;
    bool edo = (e0 < EE);              // EE even, e0 even -> e0+1 < EE too
    if (edo) {
        int2 rr = *(const int2*)(row + e0);
        int2 cc = *(const int2*)(col + e0);
        sc0 = cc.x; sc1 = cc.y;
        sp0 = atomicAdd(&wr[rr.x], 1);
        sp1 = atomicAdd(&wr[rr.y], 1);
    }

    const int wave = tid >> 6, lane = tid & 63;
    const int wm = wave & 1, wn = wave >> 1;
    const int bm = (bid % GM1_M) * BM;
    const int bnb = bid / GM1_M;
    const int bn = bnb * BN;
    const int q = lane >> 4, lr = lane & 15;

    f32x4 acc[4][NT] = {};

    for (int k0 = 0; k0 < K; k0 += BK) {
        #pragma unroll
        for (int c = wave; c < (BM * BK) / 512; c += 4) {
            int f = c * 512 + lane * 8;
            int r_ = f >> 5, ck = f & 31;
            load_lds_128(A + (size_t)(bm + r_) * K + k0 + ck, As + c * 512);
        }
        #pragma unroll
        for (int c = wave; c < (BN * BK) / 512; c += 4) {
            int f = c * 512 + lane * 8;
            int r_ = f >> 5, ck = f & 31;
            load_lds_128(Bt + (size_t)(bn + r_) * K + k0 + ck, Bs + c * 512);
        }
        __syncthreads();
        frag8 af[4], bfr[NT];
        #pragma unroll
        for (int am = 0; am < 4; am++)
            af[am] = *(const frag8*)(As + (wm * 64 + am * 16 + lr) * 32 + q * 8);
        #pragma unroll
        for (int bt = 0; bt < NT; bt++)
            bfr[bt] = *(const frag8*)(Bs + (wn * WN + bt * 16 + lr) * 32 + q * 8);
        #pragma unroll
        for (int am = 0; am < 4; am++)
            #pragma unroll
            for (int bt = 0; bt < NT; bt++)
                acc[am][bt] = __builtin_amdgcn_mfma_f32_16x16x32_bf16(af[am], bfr[bt], acc[am][bt], 0, 0, 0);
        __syncthreads();
    }

    // ---- deferred scatter writes (atomic returns consumed here, latency hidden) ----
    if (edo) {
        ecol[sp0] = sc0;
        ecol[sp1] = sc1;
    }

    const int hd = bnb * 2 + wn;
    const float* ah = av + hd * 128;
    float adv[NT], adv2[NT];
    #pragma unroll
    for (int bt = 0; bt < NT; bt++) {
        adv[bt]  = ah[bt * 16 + lr];
        adv2[bt] = ah[64 + bt * 16 + lr];
    }

    #pragma unroll
    for (int am = 0; am < 4; am++) {
        #pragma unroll
        for (int reg = 0; reg < 4; reg++) {
            int gr = bm + wm * 64 + am * 16 + q * 4 + reg;
            bool inb = gr < M;
            if (inb) {
                #pragma unroll
                for (int bt = 0; bt < NT; bt++) {
                    int gc = bn + wn * WN + bt * 16 + lr;
                    C[(size_t)gr * N + gc] = f2bf(acc[am][bt][reg]);
                }
            }
            float sd = 0.f, ss = 0.f;
            #pragma unroll
            for (int bt = 0; bt < NT; bt++) {
                float v = acc[am][bt][reg];
                sd += v * adv[bt];
                ss += v * adv2[bt];
            }
            #pragma unroll
            for (int o = 1; o < 16; o <<= 1) {
                sd += __shfl_xor(sd, o);
                ss += __shfl_xor(ss, o);
            }
            if (lr == 0 && inb) {
                fd[gr * 8 + hd] = sd;
                fs[gr * 8 + hd] = ss;
            }
        }
    }
}

// -------------------- layer-2 GEMM (template, FUSE=2) --------------------
template <int BN, int OUT_MODE, int FUSE>
__global__ __launch_bounds__(256) void gemm_bf16(const u16* __restrict__ A,
                                                 const u16* __restrict__ Bt,
                                                 void* __restrict__ Cv,
                                                 int M, int N, int K,
                                                 const float* __restrict__ av,
                                                 float* __restrict__ fd,
                                                 float* __restrict__ fs) {
    constexpr int BM = 128, BK = 32;
    constexpr int WN = BN / 2;
    constexpr int NT = WN / 16;
    __shared__ u16 As[BM * BK];
    __shared__ u16 Bs[BN * BK];
    __shared__ float pd[2][2][64];
    __shared__ float ps[2][2][64];
    const int tid = threadIdx.x;
    const int wave = tid >> 6, lane = tid & 63;
    const int wm = wave & 1, wn = wave >> 1;
    const int bm = blockIdx.x * BM, bn = blockIdx.y * BN;
    const int q = lane >> 4, lr = lane & 15;

    f32x4 acc[4][NT] = {};

    for (int k0 = 0; k0 < K; k0 += BK) {
        #pragma unroll
        for (int c = wave; c < (BM * BK) / 512; c += 4) {
            int f = c * 512 + lane * 8;
            int row = f >> 5, ck = f & 31;
            load_lds_128(A + (size_t)(bm + row) * K + k0 + ck, As + c * 512);
        }
        #pragma unroll
        for (int c = wave; c < (BN * BK) / 512; c += 4) {
            int f = c * 512 + lane * 8;
            int row = f >> 5, ck = f & 31;
            load_lds_128(Bt + (size_t)(bn + row) * K + k0 + ck, Bs + c * 512);
        }
        __syncthreads();
        frag8 af[4], bfr[NT];
        #pragma unroll
        for (int am = 0; am < 4; am++)
            af[am] = *(const frag8*)(As + (wm * 64 + am * 16 + lr) * 32 + q * 8);
        #pragma unroll
        for (int bt = 0; bt < NT; bt++)
            bfr[bt] = *(const frag8*)(Bs + (wn * WN + bt * 16 + lr) * 32 + q * 8);
        #pragma unroll
        for (int am = 0; am < 4; am++)
            #pragma unroll
            for (int bt = 0; bt < NT; bt++)
                acc[am][bt] = __builtin_amdgcn_mfma_f32_16x16x32_bf16(af[am], bfr[bt], acc[am][bt], 0, 0, 0);
        __syncthreads();
    }

    float adv[NT], adv2[NT];
    int hd = 0;
    if (FUSE == 1) {
        hd = blockIdx.y * 2 + wn;
        const float* ah = av + hd * 128;
        #pragma unroll
        for (int bt = 0; bt < NT; bt++) {
            adv[bt]  = ah[bt * 16 + lr];
            adv2[bt] = ah[64 + bt * 16 + lr];
        }
    }
    if (FUSE == 2) {
        #pragma unroll
        for (int bt = 0; bt < NT; bt++) {
            adv[bt]  = av[wn * WN + bt * 16 + lr];
            adv2[bt] = av[64 + wn * WN + bt * 16 + lr];
        }
    }

    #pragma unroll
    for (int am = 0; am < 4; am++) {
        #pragma unroll
        for (int reg = 0; reg < 4; reg++) {
            int gr = bm + wm * 64 + am * 16 + q * 4 + reg;
            bool inb = gr < M;
            if (inb) {
                #pragma unroll
                for (int bt = 0; bt < NT; bt++) {
                    int gc = bn + wn * WN + bt * 16 + lr;
                    float v = acc[am][bt][reg];
                    if (OUT_MODE == 0) ((float*)Cv)[(size_t)gr * N + gc] = v;
                    else               ((u16*)Cv)[(size_t)gr * N + gc] = f2bf(v);
                }
            }
            if (FUSE != 0) {
                float sd = 0.f, ss = 0.f;
                #pragma unroll
                for (int bt = 0; bt < NT; bt++) {
                    float v = acc[am][bt][reg];
                    sd += v * adv[bt];
                    ss += v * adv2[bt];
                }
                #pragma unroll
                for (int o = 1; o < 16; o <<= 1) {
                    sd += __shfl_xor(sd, o);
                    ss += __shfl_xor(ss, o);
                }
                if (FUSE == 1) {
                    if (lr == 0 && inb) {
                        fd[gr * 8 + hd] = sd;
                        fs[gr * 8 + hd] = ss;
                    }
                } else {
                    if (lr == 0) {
                        int rr = am * 16 + q * 4 + reg;
                        pd[wm][wn][rr] = sd;
                        ps[wm][wn][rr] = ss;
                    }
                }
            }
        }
    }
    if (FUSE == 2) {
        __syncthreads();
        if (tid < 128) {
            int wmm = tid >> 6, rr = tid & 63;
            int gr = bm + wmm * 64 + rr;
            if (gr < M) {
                fd[gr] = pd[wmm][0][rr] + pd[wmm][1][rr];
                fs[gr] = ps[wmm][0][rr] + ps[wmm][1][rr];
            }
        }
    }
}

// -------------------- single-pass softmax-gather (layer 1) --------------------
__global__ __launch_bounds__(256) void agg1_fused(const int* __restrict__ start,
                                                  const int* __restrict__ ecol,
                                                  const float* __restrict__ fd,
                                                  const float* __restrict__ fs,
                                                  const u16* __restrict__ Whb,
                                                  u16* __restrict__ h1b) {
    const int i = blockIdx.x * 4 + (threadIdx.x >> 6);
    const int lane = threadIdx.x & 63;
    const int hh = lane >> 3;
    const int st = start[i], en = start[i + 1];
    const float fdv = fd[i * 8 + hh];

    float acc[8] = {};
    float den = 0.f;
    int t = st;
    for (; t + 2 <= en; t += 2) {
        int j0 = ecol[t], j1 = ecol[t + 1];
        float v0 = fdv + fs[j0 * 8 + hh]; v0 = v0 > 0.f ? v0 : ALPHA_LRELU * v0;
        float v1 = fdv + fs[j1 * 8 + hh]; v1 = v1 > 0.f ? v1 : ALPHA_LRELU * v1;
        float p0 = __expf(v0);
        float p1 = __expf(v1);
        ushort8 w0 = *(const ushort8*)(Whb + (size_t)j0 * HID_TOT + lane * 8);
        ushort8 w1 = *(const ushort8*)(Whb + (size_t)j1 * HID_TOT + lane * 8);
        den += p0 + p1;
        #pragma unroll
        for (int k = 0; k < 8; k++) acc[k] += p0 * bf2f(w0[k]);
        #pragma unroll
        for (int k = 0; k < 8; k++) acc[k] += p1 * bf2f(w1[k]);
    }
    if (t < en) {
        int j = ecol[t];
        float v = fdv + fs[j * 8 + hh]; v = v > 0.f ? v : ALPHA_LRELU * v;
        float p = __expf(v);
        den += p;
        ushort8 wv = *(const ushort8*)(Whb + (size_t)j * HID_TOT + lane * 8);
        #pragma unroll
        for (int k = 0; k < 8; k++) acc[k] += p * bf2f(wv[k]);
    }
    float rden = 1.0f / fmaxf(den, 1e-16f);
    ushort8 o8;
    #pragma unroll
    for (int k = 0; k < 8; k++) {
        float v = acc[k] * rden;
        v = v > 0.f ? v : (__expf(v) - 1.0f);
        o8[k] = f2bf(v);
    }
    *(ushort8*)(h1b + (size_t)i * HID_TOT + lane * 8) = o8;
}

// -------------------- single-pass softmax-gather (layer 2) --------------------
__global__ __launch_bounds__(256) void agg2_fused(const int* __restrict__ start,
                                                  const int* __restrict__ ecol,
                                                  const float* __restrict__ fd,
                                                  const float* __restrict__ fs,
                                                  const u16* __restrict__ Wh2b,
                                                  float* __restrict__ out) {
    const int i = blockIdx.x * 4 + (threadIdx.x >> 6);
    const int lane = threadIdx.x & 63;
    const int g = lane >> 4, r = lane & 15;
    const int st = start[i], en = start[i + 1];
    const float fdv = fd[i];

    float acc[4] = {};
    float den = 0.f;
    for (int t = st + g; t < en; t += 4) {
        int j = ecol[t];
        float v = fdv + fs[j];
        v = v > 0.f ? v : ALPHA_LRELU * v;
        float p = __expf(v);
        den += p;
        ushort4v wv = *(const ushort4v*)(Wh2b + (size_t)j * NCLASS + r * 4);
        #pragma unroll
        for (int k = 0; k < 4; k++) acc[k] += p * bf2f(wv[k]);
    }
    #pragma unroll
    for (int o = 16; o <= 32; o <<= 1) {
        den += __shfl_xor(den, o);
        #pragma unroll
        for (int k = 0; k < 4; k++) acc[k] += __shfl_xor(acc[k], o);
    }
    if (g == 0) {
        float rden = 1.0f / fmaxf(den, 1e-16f);
        float4 o4;
        o4.x = acc[0] * rden; o4.y = acc[1] * rden;
        o4.z = acc[2] * rden; o4.w = acc[3] * rden;
        *(float4*)(out + (size_t)i * NCLASS + r * 4) = o4;
    }
}

// -------------------- launch --------------------

static inline int cdiv_l(long a, long b) { return (int)((a + b - 1) / b); }

extern "C" void kernel_launch(void* const* d_in, const int* in_sizes, int n_in,
                              void* d_out, int out_size, void* d_ws, size_t ws_size,
                              hipStream_t stream) {
    const float* x     = (const float*)d_in[0];
    const int*   row   = (const int*)d_in[1];
    const int*   col   = (const int*)d_in[2];
    const float* W     = (const float*)d_in[3];
    const float* a     = (const float*)d_in[4];
    const float* W_out = (const float*)d_in[5];
    const float* a_out = (const float*)d_in[6];
    float* out = (float*)d_out;

    char* wsb = (char*)d_ws;
    size_t off = 0;
    auto alloc = [&](size_t bytes) { char* p = wsb + off; off += (bytes + 255) & ~(size_t)255; return p; };
    u16*   xb     = (u16*)  alloc((size_t)MPAD * 512 * 2);
    u16*   Wcat_t = (u16*)  alloc((size_t)512 * 512 * 2);
    u16*   Wot_t  = (u16*)  alloc((size_t)64 * 512 * 2);
    u16*   Whb1   = (u16*)  alloc((size_t)NN * 512 * 2);
    float* fd1    = (float*)alloc((size_t)NN * 8 * 4);
    float* fs1    = (float*)alloc((size_t)NN * 8 * 4);
    u16*   h1b    = (u16*)  alloc((size_t)MPAD * 512 * 2);
    u16*   Wh2b   = (u16*)  alloc((size_t)NN * 64 * 2);
    float* fd2    = (float*)alloc((size_t)NN * 4);
    float* fs2    = (float*)alloc((size_t)NN * 4);
    int*   cnt    = (int*)  alloc((size_t)NN * 4);
    int*   startp = (int*)  alloc(((size_t)NN + 1) * 4);
    int*   wr     = (int*)  alloc((size_t)NN * 4);
    int*   ecol   = (int*)  alloc((size_t)EE * 4);
    int*   bsum   = (int*)  alloc((size_t)NB1 * 4);
    int*   boff   = (int*)  alloc((size_t)NB1 * 4);
    (void)boff;

    // ---- zero cnt (memset node), then prep ∥ hist in one kernel ----
    hipMemsetAsync(cnt, 0, (size_t)NN * 4, stream);
    prep_all<<<cdiv_l(PREP_TOT, 256), 256, 0, stream>>>(x, W, W_out, xb, Wcat_t, Wot_t,
                                                        row, cnt);

    // ---- CSR scan (boff inlined into scan_write) ----
    scan_blocksum<<<NB1, 256, 0, stream>>>(cnt, bsum);
    scan_write<<<NB1, 256, 0, stream>>>(cnt, bsum, startp, wr);

    // ---- layer-1 GEMM with scatter folded into every block ----
    scat_gemm1<<<GM1_B, 256, 0, stream>>>(row, col, wr, ecol,
                                          xb, Wcat_t, Whb1, a, fd1, fs1);

    agg1_fused<<<NN / 4, 256, 0, stream>>>(startp, ecol, fd1, fs1, Whb1, h1b);

    // ---- layer 2 ----
    {
        dim3 grid(cdiv_l(MPAD, 128), 1);
        gemm_bf16<64, 1, 2><<<grid, 256, 0, stream>>>(h1b, Wot_t, Wh2b, NN, 64, 512,
                                                      a_out, fd2, fs2);
    }
    agg2_fused<<<NN / 4, 256, 0, stream>>>(startp, ecol, fd2, fs2, Wh2b, out);
}

// Round 13
// 468.926 us; speedup vs baseline: 1.1529x; 1.0070x over previous
//
#include <hip/hip_runtime.h>
#include <cstdint>
#include <cstddef>

#define NN      50000
#define MPAD    50048   // NN padded to 128
#define EE      800000
#define NHEADS  8
#define HID_TOT 512
#define NCLASS  64
#define ALPHA_LRELU 0.2f
#define NB1     196     // cdiv(NN,256)
#define GM1_M   391     // MPAD/128 panels in gemm1
#define GM1_B   (GM1_M * 4)   // 1564 blocks; x2 edges/thread covers EE=800000

typedef unsigned short u16;
typedef __attribute__((ext_vector_type(8))) unsigned short ushort8;
typedef __attribute__((ext_vector_type(4))) unsigned short ushort4v;

__device__ __forceinline__ float bf2f(u16 v) {
    return __uint_as_float(((unsigned)v) << 16);
}
__device__ __forceinline__ u16 f2bf(float f) {   // round-to-nearest-even
    unsigned u = __float_as_uint(f);
    return (u16)((u + 0x7fffu + ((u >> 16) & 1u)) >> 16);
}

// -------------------- fused prep: cast_x + pack_w1t + pack_woutt + hist --------------------
#define PREP_R0 (MPAD * 64)          // cast_x groups (8 elems each)
#define PREP_R1 (512 * 512)          // pack_w1t elems
#define PREP_R2 (64 * 512)           // pack_woutt elems
#define PREP_TOT (PREP_R0 + PREP_R1 + PREP_R2 + EE)

__global__ __launch_bounds__(256) void prep_all(const float* __restrict__ x,
                                                const float* __restrict__ W,
                                                const float* __restrict__ W_out,
                                                u16* __restrict__ xb,
                                                u16* __restrict__ Wt1,
                                                u16* __restrict__ Wto,
                                                const int* __restrict__ row,
                                                int* __restrict__ cnt) {
    int g = blockIdx.x * 256 + threadIdx.x;
    if (g < PREP_R0) {
        int r = g >> 6;
        int c = (g & 63) * 8;
        ushort8 o = (ushort8)0;
        if (r < NN) {
            const float4 v0 = *(const float4*)(x + (size_t)r * 512 + c);
            const float4 v1 = *(const float4*)(x + (size_t)r * 512 + c + 4);
            o[0] = f2bf(v0.x); o[1] = f2bf(v0.y); o[2] = f2bf(v0.z); o[3] = f2bf(v0.w);
            o[4] = f2bf(v1.x); o[5] = f2bf(v1.y); o[6] = f2bf(v1.z); o[7] = f2bf(v1.w);
        }
        *(ushort8*)(xb + (size_t)r * 512 + c) = o;
        return;
    }
    g -= PREP_R0;
    if (g < PREP_R1) {
        int c = g >> 9, f = g & 511;
        int h = c >> 6, j = c & 63;
        Wt1[g] = f2bf(W[(h << 15) + (f << 6) + j]);
        return;
    }
    g -= PREP_R1;
    if (g < PREP_R2) {
        int n = g >> 9, k = g & 511;
        Wto[g] = f2bf(W_out[k * 64 + n]);
        return;
    }
    g -= PREP_R2;
    if (g < EE) {
        atomicAdd(&cnt[row[g]], 1);
    }
}

// -------------------- CSR build --------------------

__global__ __launch_bounds__(256) void scan_blocksum(const int* __restrict__ cnt,
                                                     int* __restrict__ bsum) {
    int idx = blockIdx.x * 256 + threadIdx.x;
    int v = (idx < NN) ? cnt[idx] : 0;
    #pragma unroll
    for (int o = 32; o; o >>= 1) v += __shfl_xor(v, o);
    __shared__ int sw[4];
    int wave = threadIdx.x >> 6;
    if ((threadIdx.x & 63) == 0) sw[wave] = v;
    __syncthreads();
    if (threadIdx.x == 0) bsum[blockIdx.x] = sw[0] + sw[1] + sw[2] + sw[3];
}

// scan_write with the inter-block offset computed inline (scan_bsums eliminated).
__global__ __launch_bounds__(256) void scan_write(const int* __restrict__ cnt,
                                                  const int* __restrict__ bsum,
                                                  int* __restrict__ start,
                                                  int* __restrict__ wr) {
    __shared__ int sh[256];
    __shared__ int swb[4];
    int t = threadIdx.x;
    int vb = (t < NB1 && t < blockIdx.x) ? bsum[t] : 0;
    #pragma unroll
    for (int o = 32; o; o >>= 1) vb += __shfl_xor(vb, o);
    if ((t & 63) == 0) swb[t >> 6] = vb;
    __syncthreads();
    const int blockoff = swb[0] + swb[1] + swb[2] + swb[3];

    int idx = blockIdx.x * 256 + t;
    int c = (idx < NN) ? cnt[idx] : 0;
    __syncthreads();
    sh[t] = c;
    __syncthreads();
    for (int o = 1; o < 256; o <<= 1) {
        int cur = sh[t];
        int add = (t >= o) ? sh[t - o] : 0;
        __syncthreads();
        sh[t] = cur + add;
        __syncthreads();
    }
    if (idx < NN) {
        int excl = blockoff + sh[t] - c;
        start[idx] = excl;
        wr[idx] = excl;
    }
    if (idx == 0) start[NN] = EE;
}

// -------------------- gemm1 (2-phase pipelined, statically unrolled dbuf) + folded scatter --------------------

__device__ __forceinline__ void load_lds_128(const u16* g, u16* l) {
    __builtin_amdgcn_global_load_lds((const __attribute__((address_space(1))) void*)g,
                                     (__attribute__((address_space(3))) void*)l,
                                     16, 0, 0);
}

typedef __attribute__((ext_vector_type(8))) short frag8;
typedef __attribute__((ext_vector_type(4))) float f32x4;

__global__ __launch_bounds__(256) void scat_gemm1(const int* __restrict__ row,
                                                  const int* __restrict__ col,
                                                  int* __restrict__ wr,
                                                  int* __restrict__ ecol,
                                                  const u16* __restrict__ A,
                                                  const u16* __restrict__ Bt,
                                                  u16* __restrict__ C,
                                                  const float* __restrict__ av,
                                                  float* __restrict__ fd,
                                                  float* __restrict__ fs) {
    constexpr int BM = 128, BN = 128, BK = 32, WN = 64, NT = 4;
    constexpr int M = NN, N = 512, K = 512, KT = K / BK;   // KT = 16 (even)
    __shared__ u16 As0[BM * BK], As1[BM * BK];
    __shared__ u16 Bs0[BN * BK], Bs1[BN * BK];
    const int tid = threadIdx.x;
    const int bid = blockIdx.x;

    // ---- scatter prologue: issue atomics, defer the dependent writes ----
    const int e0 = (bid * 256 + tid) * 2;
    int sc0 = 0, sc1 = 0, sp0 = 0, sp1 = 0;
    bool edo = (e0 < EE);              // EE even, e0 even -> e0+1 < EE too
    if (edo) {
        int2 rr = *(const int2*)(row + e0);
        int2 cc = *(const int2*)(col + e0);
        sc0 = cc.x; sc1 = cc.y;
        sp0 = atomicAdd(&wr[rr.x], 1);
        sp1 = atomicAdd(&wr[rr.y], 1);
    }

    const int wave = tid >> 6, lane = tid & 63;
    const int wm = wave & 1, wn = wave >> 1;
    const int bm = (bid % GM1_M) * BM;
    const int bnb = bid / GM1_M;
    const int bn = bnb * BN;
    const int q = lane >> 4, lr = lane & 15;

    f32x4 acc[4][NT] = {};

    auto stage = [&](u16* as, u16* bs, int k0) {
        #pragma unroll
        for (int c = wave; c < (BM * BK) / 512; c += 4) {
            int f = c * 512 + lane * 8;
            int r_ = f >> 5, ck = f & 31;
            load_lds_128(A + (size_t)(bm + r_) * K + k0 + ck, as + c * 512);
        }
        #pragma unroll
        for (int c = wave; c < (BN * BK) / 512; c += 4) {
            int f = c * 512 + lane * 8;
            int r_ = f >> 5, ck = f & 31;
            load_lds_128(Bt + (size_t)(bn + r_) * K + k0 + ck, bs + c * 512);
        }
    };
    auto compute = [&](const u16* as, const u16* bs) {
        frag8 af[4], bfr[NT];
        #pragma unroll
        for (int am = 0; am < 4; am++)
            af[am] = *(const frag8*)(as + (wm * 64 + am * 16 + lr) * 32 + q * 8);
        #pragma unroll
        for (int bt = 0; bt < NT; bt++)
            bfr[bt] = *(const frag8*)(bs + (wn * WN + bt * 16 + lr) * 32 + q * 8);
        #pragma unroll
        for (int am = 0; am < 4; am++)
            #pragma unroll
            for (int bt = 0; bt < NT; bt++)
                acc[am][bt] = __builtin_amdgcn_mfma_f32_16x16x32_bf16(af[am], bfr[bt], acc[am][bt], 0, 0, 0);
    };

    stage(As0, Bs0, 0);
    for (int kt = 0; kt < KT; kt += 2) {
        __syncthreads();                                    // buf0 staged (vmcnt drained)
        if (kt + 1 < KT) stage(As1, Bs1, (kt + 1) * BK);    // next tile hides under MFMA
        compute(As0, Bs0);
        __syncthreads();                                    // buf1 staged
        if (kt + 2 < KT) stage(As0, Bs0, (kt + 2) * BK);
        compute(As1, Bs1);
    }

    // ---- deferred scatter writes (atomic returns consumed here, latency hidden) ----
    if (edo) {
        ecol[sp0] = sc0;
        ecol[sp1] = sc1;
    }

    const int hd = bnb * 2 + wn;
    const float* ah = av + hd * 128;
    float adv[NT], adv2[NT];
    #pragma unroll
    for (int bt = 0; bt < NT; bt++) {
        adv[bt]  = ah[bt * 16 + lr];
        adv2[bt] = ah[64 + bt * 16 + lr];
    }

    #pragma unroll
    for (int am = 0; am < 4; am++) {
        #pragma unroll
        for (int reg = 0; reg < 4; reg++) {
            int gr = bm + wm * 64 + am * 16 + q * 4 + reg;
            bool inb = gr < M;
            if (inb) {
                #pragma unroll
                for (int bt = 0; bt < NT; bt++) {
                    int gc = bn + wn * WN + bt * 16 + lr;
                    C[(size_t)gr * N + gc] = f2bf(acc[am][bt][reg]);
                }
            }
            float sd = 0.f, ss = 0.f;
            #pragma unroll
            for (int bt = 0; bt < NT; bt++) {
                float v = acc[am][bt][reg];
                sd += v * adv[bt];
                ss += v * adv2[bt];
            }
            #pragma unroll
            for (int o = 1; o < 16; o <<= 1) {
                sd += __shfl_xor(sd, o);
                ss += __shfl_xor(ss, o);
            }
            if (lr == 0 && inb) {
                fd[gr * 8 + hd] = sd;
                fs[gr * 8 + hd] = ss;
            }
        }
    }
}

// -------------------- layer-2 GEMM (template, FUSE=2, 2-phase pipelined) --------------------
template <int BN, int OUT_MODE, int FUSE>
__global__ __launch_bounds__(256) void gemm_bf16(const u16* __restrict__ A,
                                                 const u16* __restrict__ Bt,
                                                 void* __restrict__ Cv,
                                                 int M, int N, int K,
                                                 const float* __restrict__ av,
                                                 float* __restrict__ fd,
                                                 float* __restrict__ fs) {
    constexpr int BM = 128, BK = 32;
    constexpr int WN = BN / 2;
    constexpr int NT = WN / 16;
    __shared__ u16 As0[BM * BK], As1[BM * BK];
    __shared__ u16 Bs0[BN * BK], Bs1[BN * BK];
    __shared__ float pd[2][2][64];
    __shared__ float ps[2][2][64];
    const int tid = threadIdx.x;
    const int wave = tid >> 6, lane = tid & 63;
    const int wm = wave & 1, wn = wave >> 1;
    const int bm = blockIdx.x * BM, bn = blockIdx.y * BN;
    const int q = lane >> 4, lr = lane & 15;

    f32x4 acc[4][NT] = {};

    auto stage = [&](u16* as, u16* bs, int k0) {
        #pragma unroll
        for (int c = wave; c < (BM * BK) / 512; c += 4) {
            int f = c * 512 + lane * 8;
            int row = f >> 5, ck = f & 31;
            load_lds_128(A + (size_t)(bm + row) * K + k0 + ck, as + c * 512);
        }
        #pragma unroll
        for (int c = wave; c < (BN * BK) / 512; c += 4) {
            int f = c * 512 + lane * 8;
            int row = f >> 5, ck = f & 31;
            load_lds_128(Bt + (size_t)(bn + row) * K + k0 + ck, bs + c * 512);
        }
    };
    auto compute = [&](const u16* as, const u16* bs) {
        frag8 af[4], bfr[NT];
        #pragma unroll
        for (int am = 0; am < 4; am++)
            af[am] = *(const frag8*)(as + (wm * 64 + am * 16 + lr) * 32 + q * 8);
        #pragma unroll
        for (int bt = 0; bt < NT; bt++)
            bfr[bt] = *(const frag8*)(bs + (wn * WN + bt * 16 + lr) * 32 + q * 8);
        #pragma unroll
        for (int am = 0; am < 4; am++)
            #pragma unroll
            for (int bt = 0; bt < NT; bt++)
                acc[am][bt] = __builtin_amdgcn_mfma_f32_16x16x32_bf16(af[am], bfr[bt], acc[am][bt], 0, 0, 0);
    };

    const int KT = K / BK;   // 16 for K=512 (even)
    stage(As0, Bs0, 0);
    for (int kt = 0; kt < KT; kt += 2) {
        __syncthreads();
        if (kt + 1 < KT) stage(As1, Bs1, (kt + 1) * BK);
        compute(As0, Bs0);
        __syncthreads();
        if (kt + 2 < KT) stage(As0, Bs0, (kt + 2) * BK);
        compute(As1, Bs1);
    }

    float adv[NT], adv2[NT];
    int hd = 0;
    if (FUSE == 1) {
        hd = blockIdx.y * 2 + wn;
        const float* ah = av + hd * 128;
        #pragma unroll
        for (int bt = 0; bt < NT; bt++) {
            adv[bt]  = ah[bt * 16 + lr];
            adv2[bt] = ah[64 + bt * 16 + lr];
        }
    }
    if (FUSE == 2) {
        #pragma unroll
        for (int bt = 0; bt < NT; bt++) {
            adv[bt]  = av[wn * WN + bt * 16 + lr];
            adv2[bt] = av[64 + wn * WN + bt * 16 + lr];
        }
    }

    #pragma unroll
    for (int am = 0; am < 4; am++) {
        #pragma unroll
        for (int reg = 0; reg < 4; reg++) {
            int gr = bm + wm * 64 + am * 16 + q * 4 + reg;
            bool inb = gr < M;
            if (inb) {
                #pragma unroll
                for (int bt = 0; bt < NT; bt++) {
                    int gc = bn + wn * WN + bt * 16 + lr;
                    float v = acc[am][bt][reg];
                    if (OUT_MODE == 0) ((float*)Cv)[(size_t)gr * N + gc] = v;
                    else               ((u16*)Cv)[(size_t)gr * N + gc] = f2bf(v);
                }
            }
            if (FUSE != 0) {
                float sd = 0.f, ss = 0.f;
                #pragma unroll
                for (int bt = 0; bt < NT; bt++) {
                    float v = acc[am][bt][reg];
                    sd += v * adv[bt];
                    ss += v * adv2[bt];
                }
                #pragma unroll
                for (int o = 1; o < 16; o <<= 1) {
                    sd += __shfl_xor(sd, o);
                    ss += __shfl_xor(ss, o);
                }
                if (FUSE == 1) {
                    if (lr == 0 && inb) {
                        fd[gr * 8 + hd] = sd;
                        fs[gr * 8 + hd] = ss;
                    }
                } else {
                    if (lr == 0) {
                        int rr = am * 16 + q * 4 + reg;
                        pd[wm][wn][rr] = sd;
                        ps[wm][wn][rr] = ss;
                    }
                }
            }
        }
    }
    if (FUSE == 2) {
        __syncthreads();
        if (tid < 128) {
            int wmm = tid >> 6, rr = tid & 63;
            int gr = bm + wmm * 64 + rr;
            if (gr < M) {
                fd[gr] = pd[wmm][0][rr] + pd[wmm][1][rr];
                fs[gr] = ps[wmm][0][rr] + ps[wmm][1][rr];
            }
        }
    }
}

// -------------------- single-pass softmax-gather (layer 1) --------------------
__global__ __launch_bounds__(256) void agg1_fused(const int* __restrict__ start,
                                                  const int* __restrict__ ecol,
                                                  const float* __restrict__ fd,
                                                  const float* __restrict__ fs,
                                                  const u16* __restrict__ Whb,
                                                  u16* __restrict__ h1b) {
    const int i = blockIdx.x * 4 + (threadIdx.x >> 6);
    const int lane = threadIdx.x & 63;
    const int hh = lane >> 3;
    const int st = start[i], en = start[i + 1];
    const float fdv = fd[i * 8 + hh];

    float acc[8] = {};
    float den = 0.f;
    int t = st;
    for (; t + 2 <= en; t += 2) {
        int j0 = ecol[t], j1 = ecol[t + 1];
        float v0 = fdv + fs[j0 * 8 + hh]; v0 = v0 > 0.f ? v0 : ALPHA_LRELU * v0;
        float v1 = fdv + fs[j1 * 8 + hh]; v1 = v1 > 0.f ? v1 : ALPHA_LRELU * v1;
        float p0 = __expf(v0);
        float p1 = __expf(v1);
        ushort8 w0 = *(const ushort8*)(Whb + (size_t)j0 * HID_TOT + lane * 8);
        ushort8 w1 = *(const ushort8*)(Whb + (size_t)j1 * HID_TOT + lane * 8);
        den += p0 + p1;
        #pragma unroll
        for (int k = 0; k < 8; k++) acc[k] += p0 * bf2f(w0[k]);
        #pragma unroll
        for (int k = 0; k < 8; k++) acc[k] += p1 * bf2f(w1[k]);
    }
    if (t < en) {
        int j = ecol[t];
        float v = fdv + fs[j * 8 + hh]; v = v > 0.f ? v : ALPHA_LRELU * v;
        float p = __expf(v);
        den += p;
        ushort8 wv = *(const ushort8*)(Whb + (size_t)j * HID_TOT + lane * 8);
        #pragma unroll
        for (int k = 0; k < 8; k++) acc[k] += p * bf2f(wv[k]);
    }
    float rden = 1.0f / fmaxf(den, 1e-16f);
    ushort8 o8;
    #pragma unroll
    for (int k = 0; k < 8; k++) {
        float v = acc[k] * rden;
        v = v > 0.f ? v : (__expf(v) - 1.0f);
        o8[k] = f2bf(v);
    }
    *(ushort8*)(h1b + (size_t)i * HID_TOT + lane * 8) = o8;
}

// -------------------- single-pass softmax-gather (layer 2) --------------------
__global__ __launch_bounds__(256) void agg2_fused(const int* __restrict__ start,
                                                  const int* __restrict__ ecol,
                                                  const float* __restrict__ fd,
                                                  const float* __restrict__ fs,
                                                  const u16* __restrict__ Wh2b,
                                                  float* __restrict__ out) {
    const int i = blockIdx.x * 4 + (threadIdx.x >> 6);
    const int lane = threadIdx.x & 63;
    const int g = lane >> 4, r = lane & 15;
    const int st = start[i], en = start[i + 1];
    const float fdv = fd[i];

    float acc[4] = {};
    float den = 0.f;
    for (int t = st + g; t < en; t += 4) {
        int j = ecol[t];
        float v = fdv + fs[j];
        v = v > 0.f ? v : ALPHA_LRELU * v;
        float p = __expf(v);
        den += p;
        ushort4v wv = *(const ushort4v*)(Wh2b + (size_t)j * NCLASS + r * 4);
        #pragma unroll
        for (int k = 0; k < 4; k++) acc[k] += p * bf2f(wv[k]);
    }
    #pragma unroll
    for (int o = 16; o <= 32; o <<= 1) {
        den += __shfl_xor(den, o);
        #pragma unroll
        for (int k = 0; k < 4; k++) acc[k] += __shfl_xor(acc[k], o);
    }
    if (g == 0) {
        float rden = 1.0f / fmaxf(den, 1e-16f);
        float4 o4;
        o4.x = acc[0] * rden; o4.y = acc[1] * rden;
        o4.z = acc[2] * rden; o4.w = acc[3] * rden;
        *(float4*)(out + (size_t)i * NCLASS + r * 4) = o4;
    }
}

// -------------------- launch --------------------

static inline int cdiv_l(long a, long b) { return (int)((a + b - 1) / b); }

extern "C" void kernel_launch(void* const* d_in, const int* in_sizes, int n_in,
                              void* d_out, int out_size, void* d_ws, size_t ws_size,
                              hipStream_t stream) {
    const float* x     = (const float*)d_in[0];
    const int*   row   = (const int*)d_in[1];
    const int*   col   = (const int*)d_in[2];
    const float* W     = (const float*)d_in[3];
    const float* a     = (const float*)d_in[4];
    const float* W_out = (const float*)d_in[5];
    const float* a_out = (const float*)d_in[6];
    float* out = (float*)d_out;

    char* wsb = (char*)d_ws;
    size_t off = 0;
    auto alloc = [&](size_t bytes) { char* p = wsb + off; off += (bytes + 255) & ~(size_t)255; return p; };
    u16*   xb     = (u16*)  alloc((size_t)MPAD * 512 * 2);
    u16*   Wcat_t = (u16*)  alloc((size_t)512 * 512 * 2);
    u16*   Wot_t  = (u16*)  alloc((size_t)64 * 512 * 2);
    u16*   Whb1   = (u16*)  alloc((size_t)NN * 512 * 2);
    float* fd1    = (float*)alloc((size_t)NN * 8 * 4);
    float* fs1    = (float*)alloc((size_t)NN * 8 * 4);
    u16*   h1b    = (u16*)  alloc((size_t)MPAD * 512 * 2);
    u16*   Wh2b   = (u16*)  alloc((size_t)NN * 64 * 2);
    float* fd2    = (float*)alloc((size_t)NN * 4);
    float* fs2    = (float*)alloc((size_t)NN * 4);
    int*   cnt    = (int*)  alloc((size_t)NN * 4);
    int*   startp = (int*)  alloc(((size_t)NN + 1) * 4);
    int*   wr     = (int*)  alloc((size_t)NN * 4);
    int*   ecol   = (int*)  alloc((size_t)EE * 4);
    int*   bsum   = (int*)  alloc((size_t)NB1 * 4);
    int*   boff   = (int*)  alloc((size_t)NB1 * 4);
    (void)boff;

    // ---- zero cnt (memset node), then prep ∥ hist in one kernel ----
    hipMemsetAsync(cnt, 0, (size_t)NN * 4, stream);
    prep_all<<<cdiv_l(PREP_TOT, 256), 256, 0, stream>>>(x, W, W_out, xb, Wcat_t, Wot_t,
                                                        row, cnt);

    // ---- CSR scan (boff inlined into scan_write) ----
    scan_blocksum<<<NB1, 256, 0, stream>>>(cnt, bsum);
    scan_write<<<NB1, 256, 0, stream>>>(cnt, bsum, startp, wr);

    // ---- layer-1 GEMM (2-phase pipelined) with scatter folded into every block ----
    scat_gemm1<<<GM1_B, 256, 0, stream>>>(row, col, wr, ecol,
                                          xb, Wcat_t, Whb1, a, fd1, fs1);

    agg1_fused<<<NN / 4, 256, 0, stream>>>(startp, ecol, fd1, fs1, Whb1, h1b);

    // ---- layer 2 ----
    {
        dim3 grid(cdiv_l(MPAD, 128), 1);
        gemm_bf16<64, 1, 2><<<grid, 256, 0, stream>>>(h1b, Wot_t, Wh2b, NN, 64, 512,
                                                      a_out, fd2, fs2);
    }
    agg2_fused<<<NN / 4, 256, 0, stream>>>(startp, ecol, fd2, fs2, Wh2b, out);
}

// Round 14
// 456.383 us; speedup vs baseline: 1.1845x; 1.0275x over previous
//
#include <hip/hip_runtime.h>
#include <cstdint>
#include <cstddef>

#define NN      50000
#define MPAD    50048   // NN padded to 128
#define EE      800000
#define NHEADS  8
#define HID_TOT 512
#define NCLASS  64
#define ALPHA_LRELU 0.2f
#define NB1     196     // cdiv(NN,256)
#define GM1_M   391     // MPAD/128 panels in gemm1
#define GM1_B   (GM1_M * 4)   // 1564 blocks; x2 edges/thread covers EE=800000

typedef unsigned short u16;
typedef __attribute__((ext_vector_type(8))) unsigned short ushort8;
typedef __attribute__((ext_vector_type(4))) unsigned short ushort4v;

__device__ __forceinline__ float bf2f(u16 v) {
    return __uint_as_float(((unsigned)v) << 16);
}
__device__ __forceinline__ u16 f2bf(float f) {   // round-to-nearest-even
    unsigned u = __float_as_uint(f);
    return (u16)((u + 0x7fffu + ((u >> 16) & 1u)) >> 16);
}

// -------------------- fused prep: cast_x + pack_w1t + pack_woutt + hist --------------------
#define PREP_R0 (MPAD * 64)          // cast_x groups (8 elems each)
#define PREP_R1 (512 * 512)          // pack_w1t elems
#define PREP_R2 (64 * 512)           // pack_woutt elems
#define PREP_TOT (PREP_R0 + PREP_R1 + PREP_R2 + EE)

__global__ __launch_bounds__(256) void prep_all(const float* __restrict__ x,
                                                const float* __restrict__ W,
                                                const float* __restrict__ W_out,
                                                u16* __restrict__ xb,
                                                u16* __restrict__ Wt1,
                                                u16* __restrict__ Wto,
                                                const int* __restrict__ row,
                                                int* __restrict__ cnt) {
    int g = blockIdx.x * 256 + threadIdx.x;
    if (g < PREP_R0) {
        int r = g >> 6;
        int c = (g & 63) * 8;
        ushort8 o = (ushort8)0;
        if (r < NN) {
            const float4 v0 = *(const float4*)(x + (size_t)r * 512 + c);
            const float4 v1 = *(const float4*)(x + (size_t)r * 512 + c + 4);
            o[0] = f2bf(v0.x); o[1] = f2bf(v0.y); o[2] = f2bf(v0.z); o[3] = f2bf(v0.w);
            o[4] = f2bf(v1.x); o[5] = f2bf(v1.y); o[6] = f2bf(v1.z); o[7] = f2bf(v1.w);
        }
        *(ushort8*)(xb + (size_t)r * 512 + c) = o;
        return;
    }
    g -= PREP_R0;
    if (g < PREP_R1) {
        int c = g >> 9, f = g & 511;
        int h = c >> 6, j = c & 63;
        Wt1[g] = f2bf(W[(h << 15) + (f << 6) + j]);
        return;
    }
    g -= PREP_R1;
    if (g < PREP_R2) {
        int n = g >> 9, k = g & 511;
        Wto[g] = f2bf(W_out[k * 64 + n]);
        return;
    }
    g -= PREP_R2;
    if (g < EE) {
        atomicAdd(&cnt[row[g]], 1);
    }
}

// -------------------- CSR build --------------------

__global__ __launch_bounds__(256) void scan_blocksum(const int* __restrict__ cnt,
                                                     int* __restrict__ bsum) {
    int idx = blockIdx.x * 256 + threadIdx.x;
    int v = (idx < NN) ? cnt[idx] : 0;
    #pragma unroll
    for (int o = 32; o; o >>= 1) v += __shfl_xor(v, o);
    __shared__ int sw[4];
    int wave = threadIdx.x >> 6;
    if ((threadIdx.x & 63) == 0) sw[wave] = v;
    __syncthreads();
    if (threadIdx.x == 0) bsum[blockIdx.x] = sw[0] + sw[1] + sw[2] + sw[3];
}

// scan_write with the inter-block offset computed inline (scan_bsums eliminated).
__global__ __launch_bounds__(256) void scan_write(const int* __restrict__ cnt,
                                                  const int* __restrict__ bsum,
                                                  int* __restrict__ start,
                                                  int* __restrict__ wr) {
    __shared__ int sh[256];
    __shared__ int swb[4];
    int t = threadIdx.x;
    int vb = (t < NB1 && t < blockIdx.x) ? bsum[t] : 0;
    #pragma unroll
    for (int o = 32; o; o >>= 1) vb += __shfl_xor(vb, o);
    if ((t & 63) == 0) swb[t >> 6] = vb;
    __syncthreads();
    const int blockoff = swb[0] + swb[1] + swb[2] + swb[3];

    int idx = blockIdx.x * 256 + t;
    int c = (idx < NN) ? cnt[idx] : 0;
    __syncthreads();
    sh[t] = c;
    __syncthreads();
    for (int o = 1; o < 256; o <<= 1) {
        int cur = sh[t];
        int add = (t >= o) ? sh[t - o] : 0;
        __syncthreads();
        sh[t] = cur + add;
        __syncthreads();
    }
    if (idx < NN) {
        int excl = blockoff + sh[t] - c;
        start[idx] = excl;
        wr[idx] = excl;
    }
    if (idx == 0) start[NN] = EE;
}

// -------------------- gemm1: 3-buffer counted-vmcnt pipeline (T4) + folded scatter --------------------
// Phase boundary = raw "s_waitcnt vmcnt(4); s_barrier" (NOT __syncthreads, which drains
// vmcnt(0)): tile kt+1's 4 loads/thread stay in flight ACROSS the barrier. 2 tiles ahead,
// 3 LDS buffer pairs, fully unrolled so all buffer indices are compile-time.

__device__ __forceinline__ void load_lds_128(const u16* g, u16* l) {
    __builtin_amdgcn_global_load_lds((const __attribute__((address_space(1))) void*)g,
                                     (__attribute__((address_space(3))) void*)l,
                                     16, 0, 0);
}

typedef __attribute__((ext_vector_type(8))) short frag8;
typedef __attribute__((ext_vector_type(4))) float f32x4;

__global__ __launch_bounds__(256) void scat_gemm1(const int* __restrict__ row,
                                                  const int* __restrict__ col,
                                                  int* __restrict__ wr,
                                                  int* __restrict__ ecol,
                                                  const u16* __restrict__ A,
                                                  const u16* __restrict__ Bt,
                                                  u16* __restrict__ C,
                                                  const float* __restrict__ av,
                                                  float* __restrict__ fd,
                                                  float* __restrict__ fs) {
    constexpr int BM = 128, BN = 128, BK = 32, WN = 64, NT = 4;
    constexpr int M = NN, N = 512, K = 512, KT = K / BK;   // KT = 16
    __shared__ u16 AsB[3][BM * BK];
    __shared__ u16 BsB[3][BN * BK];
    const int tid = threadIdx.x;
    const int bid = blockIdx.x;

    // ---- scatter prologue: issue atomics, defer the dependent writes ----
    // (the 2 atomics are the oldest vmcnt ops; iter-0's vmcnt(4) absorbs them)
    const int e0 = (bid * 256 + tid) * 2;
    int sc0 = 0, sc1 = 0, sp0 = 0, sp1 = 0;
    bool edo = (e0 < EE);              // EE even, e0 even -> e0+1 < EE too
    if (edo) {
        int2 rr = *(const int2*)(row + e0);
        int2 cc = *(const int2*)(col + e0);
        sc0 = cc.x; sc1 = cc.y;
        sp0 = atomicAdd(&wr[rr.x], 1);
        sp1 = atomicAdd(&wr[rr.y], 1);
    }

    const int wave = tid >> 6, lane = tid & 63;
    const int wm = wave & 1, wn = wave >> 1;
    const int bm = (bid % GM1_M) * BM;
    const int bnb = bid / GM1_M;
    const int bn = bnb * BN;
    const int q = lane >> 4, lr = lane & 15;

    f32x4 acc[4][NT] = {};

    // stage = exactly 4 global_load_lds per thread (2 A + 2 B), uniform across threads
    auto stage = [&](u16* as, u16* bs, int k0) {
        #pragma unroll
        for (int c = wave; c < (BM * BK) / 512; c += 4) {
            int f = c * 512 + lane * 8;
            int r_ = f >> 5, ck = f & 31;
            load_lds_128(A + (size_t)(bm + r_) * K + k0 + ck, as + c * 512);
        }
        #pragma unroll
        for (int c = wave; c < (BN * BK) / 512; c += 4) {
            int f = c * 512 + lane * 8;
            int r_ = f >> 5, ck = f & 31;
            load_lds_128(Bt + (size_t)(bn + r_) * K + k0 + ck, bs + c * 512);
        }
    };
    auto compute = [&](const u16* as, const u16* bs) {
        frag8 af[4], bfr[NT];
        #pragma unroll
        for (int am = 0; am < 4; am++)
            af[am] = *(const frag8*)(as + (wm * 64 + am * 16 + lr) * 32 + q * 8);
        #pragma unroll
        for (int bt = 0; bt < NT; bt++)
            bfr[bt] = *(const frag8*)(bs + (wn * WN + bt * 16 + lr) * 32 + q * 8);
        #pragma unroll
        for (int am = 0; am < 4; am++)
            #pragma unroll
            for (int bt = 0; bt < NT; bt++)
                acc[am][bt] = __builtin_amdgcn_mfma_f32_16x16x32_bf16(af[am], bfr[bt], acc[am][bt], 0, 0, 0);
    };

    stage(AsB[0], BsB[0], 0);
    stage(AsB[1], BsB[1], BK);
    #pragma unroll
    for (int kt = 0; kt < KT; kt++) {
        // wait for tile kt (leave tile kt+1 in flight), then raw barrier.
        if (kt < KT - 1) asm volatile("s_waitcnt vmcnt(4)\n\ts_barrier" ::: "memory");
        else             asm volatile("s_waitcnt vmcnt(0)\n\ts_barrier" ::: "memory");
        if (kt + 2 < KT) stage(AsB[(kt + 2) % 3], BsB[(kt + 2) % 3], (kt + 2) * BK);
        compute(AsB[kt % 3], BsB[kt % 3]);
    }

    // ---- deferred scatter writes (atomic returns long since landed) ----
    if (edo) {
        ecol[sp0] = sc0;
        ecol[sp1] = sc1;
    }

    const int hd = bnb * 2 + wn;
    const float* ah = av + hd * 128;
    float adv[NT], adv2[NT];
    #pragma unroll
    for (int bt = 0; bt < NT; bt++) {
        adv[bt]  = ah[bt * 16 + lr];
        adv2[bt] = ah[64 + bt * 16 + lr];
    }

    #pragma unroll
    for (int am = 0; am < 4; am++) {
        #pragma unroll
        for (int reg = 0; reg < 4; reg++) {
            int gr = bm + wm * 64 + am * 16 + q * 4 + reg;
            bool inb = gr < M;
            if (inb) {
                #pragma unroll
                for (int bt = 0; bt < NT; bt++) {
                    int gc = bn + wn * WN + bt * 16 + lr;
                    C[(size_t)gr * N + gc] = f2bf(acc[am][bt][reg]);
                }
            }
            float sd = 0.f, ss = 0.f;
            #pragma unroll
            for (int bt = 0; bt < NT; bt++) {
                float v = acc[am][bt][reg];
                sd += v * adv[bt];
                ss += v * adv2[bt];
            }
            #pragma unroll
            for (int o = 1; o < 16; o <<= 1) {
                sd += __shfl_xor(sd, o);
                ss += __shfl_xor(ss, o);
            }
            if (lr == 0 && inb) {
                fd[gr * 8 + hd] = sd;
                fs[gr * 8 + hd] = ss;
            }
        }
    }
}

// -------------------- layer-2 GEMM (template, FUSE=2, 2-phase pipelined — proven r13 form) --------------------
template <int BN, int OUT_MODE, int FUSE>
__global__ __launch_bounds__(256) void gemm_bf16(const u16* __restrict__ A,
                                                 const u16* __restrict__ Bt,
                                                 void* __restrict__ Cv,
                                                 int M, int N, int K,
                                                 const float* __restrict__ av,
                                                 float* __restrict__ fd,
                                                 float* __restrict__ fs) {
    constexpr int BM = 128, BK = 32;
    constexpr int WN = BN / 2;
    constexpr int NT = WN / 16;
    __shared__ u16 As0[BM * BK], As1[BM * BK];
    __shared__ u16 Bs0[BN * BK], Bs1[BN * BK];
    __shared__ float pd[2][2][64];
    __shared__ float ps[2][2][64];
    const int tid = threadIdx.x;
    const int wave = tid >> 6, lane = tid & 63;
    const int wm = wave & 1, wn = wave >> 1;
    const int bm = blockIdx.x * BM, bn = blockIdx.y * BN;
    const int q = lane >> 4, lr = lane & 15;

    f32x4 acc[4][NT] = {};

    auto stage = [&](u16* as, u16* bs, int k0) {
        #pragma unroll
        for (int c = wave; c < (BM * BK) / 512; c += 4) {
            int f = c * 512 + lane * 8;
            int row = f >> 5, ck = f & 31;
            load_lds_128(A + (size_t)(bm + row) * K + k0 + ck, as + c * 512);
        }
        #pragma unroll
        for (int c = wave; c < (BN * BK) / 512; c += 4) {
            int f = c * 512 + lane * 8;
            int row = f >> 5, ck = f & 31;
            load_lds_128(Bt + (size_t)(bn + row) * K + k0 + ck, bs + c * 512);
        }
    };
    auto compute = [&](const u16* as, const u16* bs) {
        frag8 af[4], bfr[NT];
        #pragma unroll
        for (int am = 0; am < 4; am++)
            af[am] = *(const frag8*)(as + (wm * 64 + am * 16 + lr) * 32 + q * 8);
        #pragma unroll
        for (int bt = 0; bt < NT; bt++)
            bfr[bt] = *(const frag8*)(bs + (wn * WN + bt * 16 + lr) * 32 + q * 8);
        #pragma unroll
        for (int am = 0; am < 4; am++)
            #pragma unroll
            for (int bt = 0; bt < NT; bt++)
                acc[am][bt] = __builtin_amdgcn_mfma_f32_16x16x32_bf16(af[am], bfr[bt], acc[am][bt], 0, 0, 0);
    };

    const int KT = K / BK;   // 16 for K=512 (even)
    stage(As0, Bs0, 0);
    for (int kt = 0; kt < KT; kt += 2) {
        __syncthreads();
        if (kt + 1 < KT) stage(As1, Bs1, (kt + 1) * BK);
        compute(As0, Bs0);
        __syncthreads();
        if (kt + 2 < KT) stage(As0, Bs0, (kt + 2) * BK);
        compute(As1, Bs1);
    }

    float adv[NT], adv2[NT];
    int hd = 0;
    if (FUSE == 1) {
        hd = blockIdx.y * 2 + wn;
        const float* ah = av + hd * 128;
        #pragma unroll
        for (int bt = 0; bt < NT; bt++) {
            adv[bt]  = ah[bt * 16 + lr];
            adv2[bt] = ah[64 + bt * 16 + lr];
        }
    }
    if (FUSE == 2) {
        #pragma unroll
        for (int bt = 0; bt < NT; bt++) {
            adv[bt]  = av[wn * WN + bt * 16 + lr];
            adv2[bt] = av[64 + wn * WN + bt * 16 + lr];
        }
    }

    #pragma unroll
    for (int am = 0; am < 4; am++) {
        #pragma unroll
        for (int reg = 0; reg < 4; reg++) {
            int gr = bm + wm * 64 + am * 16 + q * 4 + reg;
            bool inb = gr < M;
            if (inb) {
                #pragma unroll
                for (int bt = 0; bt < NT; bt++) {
                    int gc = bn + wn * WN + bt * 16 + lr;
                    float v = acc[am][bt][reg];
                    if (OUT_MODE == 0) ((float*)Cv)[(size_t)gr * N + gc] = v;
                    else               ((u16*)Cv)[(size_t)gr * N + gc] = f2bf(v);
                }
            }
            if (FUSE != 0) {
                float sd = 0.f, ss = 0.f;
                #pragma unroll
                for (int bt = 0; bt < NT; bt++) {
                    float v = acc[am][bt][reg];
                    sd += v * adv[bt];
                    ss += v * adv2[bt];
                }
                #pragma unroll
                for (int o = 1; o < 16; o <<= 1) {
                    sd += __shfl_xor(sd, o);
                    ss += __shfl_xor(ss, o);
                }
                if (FUSE == 1) {
                    if (lr == 0 && inb) {
                        fd[gr * 8 + hd] = sd;
                        fs[gr * 8 + hd] = ss;
                    }
                } else {
                    if (lr == 0) {
                        int rr = am * 16 + q * 4 + reg;
                        pd[wm][wn][rr] = sd;
                        ps[wm][wn][rr] = ss;
                    }
                }
            }
        }
    }
    if (FUSE == 2) {
        __syncthreads();
        if (tid < 128) {
            int wmm = tid >> 6, rr = tid & 63;
            int gr = bm + wmm * 64 + rr;
            if (gr < M) {
                fd[gr] = pd[wmm][0][rr] + pd[wmm][1][rr];
                fs[gr] = ps[wmm][0][rr] + ps[wmm][1][rr];
            }
        }
    }
}

// -------------------- single-pass softmax-gather (layer 1) --------------------
__global__ __launch_bounds__(256) void agg1_fused(const int* __restrict__ start,
                                                  const int* __restrict__ ecol,
                                                  const float* __restrict__ fd,
                                                  const float* __restrict__ fs,
                                                  const u16* __restrict__ Whb,
                                                  u16* __restrict__ h1b) {
    const int i = blockIdx.x * 4 + (threadIdx.x >> 6);
    const int lane = threadIdx.x & 63;
    const int hh = lane >> 3;
    const int st = start[i], en = start[i + 1];
    const float fdv = fd[i * 8 + hh];

    float acc[8] = {};
    float den = 0.f;
    int t = st;
    for (; t + 2 <= en; t += 2) {
        int j0 = ecol[t], j1 = ecol[t + 1];
        float v0 = fdv + fs[j0 * 8 + hh]; v0 = v0 > 0.f ? v0 : ALPHA_LRELU * v0;
        float v1 = fdv + fs[j1 * 8 + hh]; v1 = v1 > 0.f ? v1 : ALPHA_LRELU * v1;
        float p0 = __expf(v0);
        float p1 = __expf(v1);
        ushort8 w0 = *(const ushort8*)(Whb + (size_t)j0 * HID_TOT + lane * 8);
        ushort8 w1 = *(const ushort8*)(Whb + (size_t)j1 * HID_TOT + lane * 8);
        den += p0 + p1;
        #pragma unroll
        for (int k = 0; k < 8; k++) acc[k] += p0 * bf2f(w0[k]);
        #pragma unroll
        for (int k = 0; k < 8; k++) acc[k] += p1 * bf2f(w1[k]);
    }
    if (t < en) {
        int j = ecol[t];
        float v = fdv + fs[j * 8 + hh]; v = v > 0.f ? v : ALPHA_LRELU * v;
        float p = __expf(v);
        den += p;
        ushort8 wv = *(const ushort8*)(Whb + (size_t)j * HID_TOT + lane * 8);
        #pragma unroll
        for (int k = 0; k < 8; k++) acc[k] += p * bf2f(wv[k]);
    }
    float rden = 1.0f / fmaxf(den, 1e-16f);
    ushort8 o8;
    #pragma unroll
    for (int k = 0; k < 8; k++) {
        float v = acc[k] * rden;
        v = v > 0.f ? v : (__expf(v) - 1.0f);
        o8[k] = f2bf(v);
    }
    *(ushort8*)(h1b + (size_t)i * HID_TOT + lane * 8) = o8;
}

// -------------------- single-pass softmax-gather (layer 2) --------------------
__global__ __launch_bounds__(256) void agg2_fused(const int* __restrict__ start,
                                                  const int* __restrict__ ecol,
                                                  const float* __restrict__ fd,
                                                  const float* __restrict__ fs,
                                                  const u16* __restrict__ Wh2b,
                                                  float* __restrict__ out) {
    const int i = blockIdx.x * 4 + (threadIdx.x >> 6);
    const int lane = threadIdx.x & 63;
    const int g = lane >> 4, r = lane & 15;
    const int st = start[i], en = start[i + 1];
    const float fdv = fd[i];

    float acc[4] = {};
    float den = 0.f;
    for (int t = st + g; t < en; t += 4) {
        int j = ecol[t];
        float v = fdv + fs[j];
        v = v > 0.f ? v : ALPHA_LRELU * v;
        float p = __expf(v);
        den += p;
        ushort4v wv = *(const ushort4v*)(Wh2b + (size_t)j * NCLASS + r * 4);
        #pragma unroll
        for (int k = 0; k < 4; k++) acc[k] += p * bf2f(wv[k]);
    }
    #pragma unroll
    for (int o = 16; o <= 32; o <<= 1) {
        den += __shfl_xor(den, o);
        #pragma unroll
        for (int k = 0; k < 4; k++) acc[k] += __shfl_xor(acc[k], o);
    }
    if (g == 0) {
        float rden = 1.0f / fmaxf(den, 1e-16f);
        float4 o4;
        o4.x = acc[0] * rden; o4.y = acc[1] * rden;
        o4.z = acc[2] * rden; o4.w = acc[3] * rden;
        *(float4*)(out + (size_t)i * NCLASS + r * 4) = o4;
    }
}

// -------------------- launch --------------------

static inline int cdiv_l(long a, long b) { return (int)((a + b - 1) / b); }

extern "C" void kernel_launch(void* const* d_in, const int* in_sizes, int n_in,
                              void* d_out, int out_size, void* d_ws, size_t ws_size,
                              hipStream_t stream) {
    const float* x     = (const float*)d_in[0];
    const int*   row   = (const int*)d_in[1];
    const int*   col   = (const int*)d_in[2];
    const float* W     = (const float*)d_in[3];
    const float* a     = (const float*)d_in[4];
    const float* W_out = (const float*)d_in[5];
    const float* a_out = (const float*)d_in[6];
    float* out = (float*)d_out;

    char* wsb = (char*)d_ws;
    size_t off = 0;
    auto alloc = [&](size_t bytes) { char* p = wsb + off; off += (bytes + 255) & ~(size_t)255; return p; };
    u16*   xb     = (u16*)  alloc((size_t)MPAD * 512 * 2);
    u16*   Wcat_t = (u16*)  alloc((size_t)512 * 512 * 2);
    u16*   Wot_t  = (u16*)  alloc((size_t)64 * 512 * 2);
    u16*   Whb1   = (u16*)  alloc((size_t)NN * 512 * 2);
    float* fd1    = (float*)alloc((size_t)NN * 8 * 4);
    float* fs1    = (float*)alloc((size_t)NN * 8 * 4);
    u16*   h1b    = (u16*)  alloc((size_t)MPAD * 512 * 2);
    u16*   Wh2b   = (u16*)  alloc((size_t)NN * 64 * 2);
    float* fd2    = (float*)alloc((size_t)NN * 4);
    float* fs2    = (float*)alloc((size_t)NN * 4);
    int*   cnt    = (int*)  alloc((size_t)NN * 4);
    int*   startp = (int*)  alloc(((size_t)NN + 1) * 4);
    int*   wr     = (int*)  alloc((size_t)NN * 4);
    int*   ecol   = (int*)  alloc((size_t)EE * 4);
    int*   bsum   = (int*)  alloc((size_t)NB1 * 4);
    int*   boff   = (int*)  alloc((size_t)NB1 * 4);
    (void)boff;

    // ---- zero cnt (memset node), then prep ∥ hist in one kernel ----
    hipMemsetAsync(cnt, 0, (size_t)NN * 4, stream);
    prep_all<<<cdiv_l(PREP_TOT, 256), 256, 0, stream>>>(x, W, W_out, xb, Wcat_t, Wot_t,
                                                        row, cnt);

    // ---- CSR scan (boff inlined into scan_write) ----
    scan_blocksum<<<NB1, 256, 0, stream>>>(cnt, bsum);
    scan_write<<<NB1, 256, 0, stream>>>(cnt, bsum, startp, wr);

    // ---- layer-1 GEMM (counted-vmcnt 3-buffer pipeline) with folded scatter ----
    scat_gemm1<<<GM1_B, 256, 0, stream>>>(row, col, wr, ecol,
                                          xb, Wcat_t, Whb1, a, fd1, fs1);

    agg1_fused<<<NN / 4, 256, 0, stream>>>(startp, ecol, fd1, fs1, Whb1, h1b);

    // ---- layer 2 ----
    {
        dim3 grid(cdiv_l(MPAD, 128), 1);
        gemm_bf16<64, 1, 2><<<grid, 256, 0, stream>>>(h1b, Wot_t, Wh2b, NN, 64, 512,
                                                      a_out, fd2, fs2);
    }
    agg2_fused<<<NN / 4, 256, 0, stream>>>(startp, ecol, fd2, fs2, Wh2b, out);
}